// Round 4
// baseline (1161.210 us; speedup 1.0000x reference)
//
#include <hip/hip_runtime.h>

#define E    512
#define H    8
#define HD   64
#define TGT  512
#define SRC  2048
#define S1   2049
#define S1P  2112     // padded source length (33 chunks of 64)
#define NB   16
#define BH   128
#define NCH  33
#define PW   2120     // P row stride in shorts: 4240 B = 16B-aligned, bank-uniform

typedef __attribute__((ext_vector_type(8))) short short8;
typedef __attribute__((ext_vector_type(4))) float floatx4;

__device__ __forceinline__ unsigned short f2bf(float x) {
    unsigned u = __float_as_uint(x);
    u = (u + 0x7FFF + ((u >> 16) & 1)) >> 16;   // round-to-nearest-even
    return (unsigned short)u;
}

// ---------------------------------------------------------------------------
// in-projection: Y = (X @ W^T + bias) * scale, fp32 inputs converted to bf16
// in-register during global->LDS staging (replaces the standalone cvt pass).
// output bf16 in [b*H+h][row][hd]
// ---------------------------------------------------------------------------
__global__ __launch_bounds__(256) void proj_gemm(const float* __restrict__ X,
    const float* __restrict__ W, const float* __restrict__ bias,
    unsigned short* __restrict__ Y, const int ld, const float scale)
{
    __shared__ __align__(16) unsigned short As[128][72];
    __shared__ __align__(16) unsigned short Bs[64][72];
    const int tid  = threadIdx.x;
    const int c0   = blockIdx.x << 6;
    const int r0   = blockIdx.y << 7;
    const int w    = tid >> 6, lane = tid & 63, c = lane & 15, quad = lane >> 4;
    floatx4 acc[2][4] = {};
    for (int k0 = 0; k0 < E; k0 += 64) {
#pragma unroll
        for (int i = 0; i < 4; ++i) {
            const int idx = tid + (i << 8);
            const int r = idx >> 3, q = (idx & 7) << 3;
            const float4 f0 = *(const float4*)&X[(size_t)(r0 + r) * E + k0 + q];
            const float4 f1 = *(const float4*)&X[(size_t)(r0 + r) * E + k0 + q + 4];
            unsigned short o[8] = {f2bf(f0.x), f2bf(f0.y), f2bf(f0.z), f2bf(f0.w),
                                   f2bf(f1.x), f2bf(f1.y), f2bf(f1.z), f2bf(f1.w)};
            *(int4*)&As[r][q] = *(int4*)o;
        }
#pragma unroll
        for (int i = 0; i < 2; ++i) {
            const int idx = tid + (i << 8);
            const int r = idx >> 3, q = (idx & 7) << 3;
            const float4 f0 = *(const float4*)&W[(size_t)(c0 + r) * E + k0 + q];
            const float4 f1 = *(const float4*)&W[(size_t)(c0 + r) * E + k0 + q + 4];
            unsigned short o[8] = {f2bf(f0.x), f2bf(f0.y), f2bf(f0.z), f2bf(f0.w),
                                   f2bf(f1.x), f2bf(f1.y), f2bf(f1.z), f2bf(f1.w)};
            *(int4*)&Bs[r][q] = *(int4*)o;
        }
        __syncthreads();
#pragma unroll
        for (int kh = 0; kh < 2; ++kh) {
            short8 a0 = *(const short8*)&As[(w << 5) + c][(kh << 5) + (quad << 3)];
            short8 a1 = *(const short8*)&As[(w << 5) + 16 + c][(kh << 5) + (quad << 3)];
#pragma unroll
            for (int n = 0; n < 4; ++n) {
                short8 b = *(const short8*)&Bs[(n << 4) + c][(kh << 5) + (quad << 3)];
                acc[0][n] = __builtin_amdgcn_mfma_f32_16x16x32_bf16(a0, b, acc[0][n], 0, 0, 0);
                acc[1][n] = __builtin_amdgcn_mfma_f32_16x16x32_bf16(a1, b, acc[1][n], 0, 0, 0);
            }
        }
        __syncthreads();
    }
#pragma unroll
    for (int mt = 0; mt < 2; ++mt) {
#pragma unroll
        for (int reg = 0; reg < 4; ++reg) {
            const int rg = r0 + (w << 5) + (mt << 4) + (quad << 2) + reg;
            const int t = rg >> 4, b = rg & 15;
#pragma unroll
            for (int n = 0; n < 4; ++n) {
                const int col = c0 + (n << 4) + c;
                const int h = col >> 6, hd = col & 63;
                const float v = (acc[mt][n][reg] + bias[col]) * scale;
                Y[((size_t)(b * H + h) * ld + t) * HD + hd] = f2bf(v);
            }
        }
    }
}

// ---------------------------------------------------------------------------
// bias columns + pad-tail zeroing, fully parallel (one store per thread).
// ---------------------------------------------------------------------------
#define FB_BIAS  8192
#define FB_KPAD  64512                       // 128 bh * 504 int4 (63 rows * 64 hd)
#define FB_VPAD  516096                      // 128 bh * 64 hd * 63 s
__global__ __launch_bounds__(256) void fill_bias(const float* __restrict__ bk,
    const float* __restrict__ bv,
    unsigned short* __restrict__ kbuf, unsigned short* __restrict__ vtbuf)
{
    const int idx = blockIdx.x * 256 + threadIdx.x;
    if (idx < FB_BIAS) {
        const int bh = idx >> 6, hd = idx & 63, h = bh & 7;
        kbuf[((size_t)bh * S1P + SRC) * HD + hd] = f2bf(bk[h * HD + hd]);
        vtbuf[((size_t)bh * HD + hd) * S1P + SRC] = f2bf(bv[h * HD + hd]);
    } else if (idx < FB_BIAS + FB_KPAD) {
        const int i = idx - FB_BIAS;
        const int bh = i / 504, o = i % 504;
        const int4 z = {0, 0, 0, 0};
        ((int4*)&kbuf[((size_t)bh * S1P + S1) * HD])[o] = z;
    } else if (idx < FB_BIAS + FB_KPAD + FB_VPAD) {
        const int i = idx - FB_BIAS - FB_KPAD;
        const int bh = i / 4032, r = i % 4032;
        const int hd = r / 63, s = S1 + r % 63;
        vtbuf[((size_t)bh * HD + hd) * S1P + s] = 0;
    }
}

// vbuf [bh][s][hd] -> vtbuf [bh][hd][s]
__global__ __launch_bounds__(256) void transpose_v(const unsigned short* __restrict__ vbuf,
    unsigned short* __restrict__ vtbuf)
{
    __shared__ __align__(16) unsigned short T[64][72];
    const int tid = threadIdx.x;
    const int s0  = blockIdx.x << 6;
    const int bh  = blockIdx.y;
#pragma unroll
    for (int i = 0; i < 2; ++i) {
        const int idx = tid + (i << 8);
        const int s = idx >> 3, q = (idx & 7) << 3;
        *(int4*)&T[s][q] = *(const int4*)&vbuf[((size_t)bh * SRC + s0 + s) * HD + q];
    }
    __syncthreads();
#pragma unroll
    for (int i = 0; i < 2; ++i) {
        const int idx = tid + (i << 8);
        const int hd = idx >> 3, sq = (idx & 7) << 3;
        unsigned short tmp[8];
#pragma unroll
        for (int j = 0; j < 8; ++j) tmp[j] = T[sq + j][hd];
        *(int4*)&vtbuf[((size_t)bh * HD + hd) * S1P + s0 + sq] = *(int4*)tmp;
    }
}

// ---------------------------------------------------------------------------
// Fused single-pass attention, 512 threads / 8 waves / 2 blocks per CU.
//  - XCD-chunked block swizzle: each XCD owns 16 bh exclusively, so per-bh
//    K/V (1.1 MB) lives in that XCD's private L2 (FETCH was 3.6x unique)
//  - phase 1: fully static 5-stage schedule, 2 K-chunks always in flight
//  - phase 3a: PV split (4 hd-slices x 2 K-halves), V prefetch depth 4
//  - phase 3b: paired b32 P reads, 8-way wave-parallel fp32 attn stores
// ---------------------------------------------------------------------------
__global__ __launch_bounds__(512, 4) void attn_fused(
    const unsigned short* __restrict__ qbh,
    const unsigned short* __restrict__ kbuf,
    const unsigned short* __restrict__ vtbuf,
    const int* __restrict__ kpm,
    float* __restrict__ attn, unsigned short* __restrict__ ctx)
{
    __shared__ __align__(16) unsigned short P[16][PW];   // 67.84 KB
    __shared__ float cpart[16][68];                      // 4.25 KB
    __shared__ float sums[8][16];
    __shared__ float linv[16];
    const int tid  = threadIdx.x;
    const int orig = blockIdx.y * 32 + blockIdx.x;       // 0..4095
    const int swz  = (orig & 7) * 512 + (orig >> 3);     // XCD-chunked, bijective
    const int t0   = (swz & 31) << 4;
    const int bh   = swz >> 5;
    const int bb   = bh >> 3;
    const int w = tid >> 6, lane = tid & 63, c = lane & 15, quad = lane >> 4;

    // Q A-fragments for this block's 16 rows (same for every wave)
    const unsigned short* qr = &qbh[((size_t)bh * TGT + t0 + c) * HD + (quad << 3)];
    short8 qa0 = *(const short8*)qr;
    short8 qa1 = *(const short8*)(qr + 32);

#define LOADK(D0, D1, M, CH) do {                                               \
        const unsigned short* kb_ = &kbuf[((size_t)bh * S1P + ((CH) << 6)) * HD]; \
        _Pragma("unroll")                                                       \
        for (int n_ = 0; n_ < 4; ++n_) {                                        \
            const unsigned short* kr_ = kb_ + ((n_ << 4) + c) * HD + (quad << 3); \
            D0[n_] = *(const short8*)kr_;                                       \
            D1[n_] = *(const short8*)(kr_ + 32);                                \
        }                                                                       \
        _Pragma("unroll")                                                       \
        for (int n_ = 0; n_ < 4; ++n_) {                                        \
            const int s_ = ((CH) << 6) + (n_ << 4) + c;                         \
            M[n_] = (s_ < SRC) ? (kpm[bb * SRC + s_] ? 3e38f : 0.f)             \
                               : ((s_ == SRC) ? 0.f : 3e38f);                   \
        }                                                                       \
    } while (0)

#define QK_COMPUTE(CH, B0, B1, M) do {                                          \
        const int s0_ = (CH) << 6;                                              \
        floatx4 sc_[4] = {};                                                    \
        _Pragma("unroll")                                                       \
        for (int n_ = 0; n_ < 4; ++n_) {                                        \
            sc_[n_] = __builtin_amdgcn_mfma_f32_16x16x32_bf16(qa0, B0[n_], sc_[n_], 0, 0, 0); \
            sc_[n_] = __builtin_amdgcn_mfma_f32_16x16x32_bf16(qa1, B1[n_], sc_[n_], 0, 0, 0); \
        }                                                                       \
        _Pragma("unroll")                                                       \
        for (int n_ = 0; n_ < 4; ++n_) {                                        \
            _Pragma("unroll")                                                   \
            for (int rg_ = 0; rg_ < 4; ++rg_) {                                 \
                const float p_ = __expf(sc_[n_][rg_] - M[n_]);                  \
                rs[rg_] += p_;                                                  \
                P[(quad << 2) + rg_][s0_ + (n_ << 4) + c] = f2bf(p_);           \
            }                                                                   \
        }                                                                       \
    } while (0)

    // ---- phase 1: QK^T + exp. wave w owns chunks {w, w+8, w+16, w+24} and
    // wave 0 additionally chunk 32. Static schedule, 2 chunks in flight. ----
    float rs[4] = {0.f, 0.f, 0.f, 0.f};
    short8 ka0[4], ka1[4], kb0[4], kb1[4];
    float ma[4], mb[4];
    LOADK(ka0, ka1, ma, w);
    LOADK(kb0, kb1, mb, w + 8);
    QK_COMPUTE(w,      ka0, ka1, ma);  LOADK(ka0, ka1, ma, w + 16);
    QK_COMPUTE(w + 8,  kb0, kb1, mb);  LOADK(kb0, kb1, mb, w + 24);
    QK_COMPUTE(w + 16, ka0, ka1, ma);
    if (w == 0) LOADK(ka0, ka1, ma, 32);
    QK_COMPUTE(w + 24, kb0, kb1, mb);
    if (w == 0) QK_COMPUTE(32, ka0, ka1, ma);

    // ---- phase 2: row-sum reduction (over c lanes, then over 8 waves) ----
#pragma unroll
    for (int reg = 0; reg < 4; ++reg) {
        float v = rs[reg];
        v += __shfl_xor(v, 1); v += __shfl_xor(v, 2);
        v += __shfl_xor(v, 4); v += __shfl_xor(v, 8);
        rs[reg] = v;
    }
    if (c == 0) {
#pragma unroll
        for (int reg = 0; reg < 4; ++reg)
            sums[w][(quad << 2) + reg] = rs[reg];
    }
    __syncthreads();
    if (tid < 16) {
        float s = 0.f;
#pragma unroll
        for (int i = 0; i < 8; ++i) s += sums[i][tid];
        linv[tid] = 1.0f / s;
    }
    __syncthreads();

    // ---- phase 3a: PV. wave -> (hd-slice hs, K-half kh2); 33 units of 32
    // columns per half; V prefetch depth 4, tail unit loaded first. ----
    const int hs = w & 3, kh2 = w >> 2;
    const int base = kh2 * 1056;
    const unsigned short* vrow = &vtbuf[((size_t)bh * HD + (hs << 4) + c) * S1P + base];
#define LV(U) (*(const short8*)&vrow[((U) << 5) + (quad << 3)])
#define LP(U) (*(const short8*)&P[c][base + ((U) << 5) + (quad << 3)])
    floatx4 ca0 = {}, ca1 = {};
    short8 vt = LV(32);
    short8 v0 = LV(0), v1 = LV(1), v2 = LV(2), v3 = LV(3);
#pragma unroll
    for (int u = 0; u < 32; u += 4) {
        ca0 = __builtin_amdgcn_mfma_f32_16x16x32_bf16(LP(u),     v0, ca0, 0, 0, 0);
        ca1 = __builtin_amdgcn_mfma_f32_16x16x32_bf16(LP(u + 1), v1, ca1, 0, 0, 0);
        if (u < 28) { v0 = LV(u + 4); v1 = LV(u + 5); }
        ca0 = __builtin_amdgcn_mfma_f32_16x16x32_bf16(LP(u + 2), v2, ca0, 0, 0, 0);
        ca1 = __builtin_amdgcn_mfma_f32_16x16x32_bf16(LP(u + 3), v3, ca1, 0, 0, 0);
        if (u < 28) { v2 = LV(u + 6); v3 = LV(u + 7); }
    }
    ca0 = __builtin_amdgcn_mfma_f32_16x16x32_bf16(LP(32), vt, ca0, 0, 0, 0);
    if (kh2 == 1) {
#pragma unroll
        for (int reg = 0; reg < 4; ++reg)
            cpart[(quad << 2) + reg][(hs << 4) + c] = ca0[reg] + ca1[reg];
    }
    __syncthreads();
    if (kh2 == 0) {
#pragma unroll
        for (int reg = 0; reg < 4; ++reg) {
            const int row = (quad << 2) + reg;
            const float v = (ca0[reg] + ca1[reg] + cpart[row][(hs << 4) + c]) * linv[row];
            ctx[((size_t)bh * TGT + t0 + row) * HD + (hs << 4) + c] = f2bf(v);
        }
    }

    // ---- phase 3b: normalized fp32 attn stores. 16 pairs of 64-col chunks
    // over 8 waves; each lane reads 2 P values per b32 LDS read. ----
    for (int p = w; p < 16; p += 8) {
        const int s0 = p << 7;
#pragma unroll
        for (int r = 0; r < 16; ++r) {
            const unsigned pk = *(const unsigned*)&P[r][s0 + (lane << 1)];
            const float li = linv[r];
            const size_t a = ((size_t)bh * TGT + t0 + r) * S1 + s0 + (lane << 1);
            attn[a]     = __uint_as_float((pk & 0xFFFFu) << 16) * li;
            attn[a + 1] = __uint_as_float(pk & 0xFFFF0000u) * li;
        }
    }
    if (w == 7 && lane < 16) {   // last real column s == 2048
        const float p = __uint_as_float((unsigned)P[lane][2048] << 16) * linv[lane];
        attn[((size_t)bh * TGT + t0 + lane) * S1 + 2048] = p;
    }
#undef LOADK
#undef QK_COMPUTE
#undef LV
#undef LP
}

// ---------------------------------------------------------------------------
// out-projection: out[r][e] = ctx_row(r) . W[e][:] + bias[e]  (fp32 out)
// ctx is bf16; W is fp32 converted during staging.
// ---------------------------------------------------------------------------
__global__ __launch_bounds__(256) void outproj_gemm(const unsigned short* __restrict__ ctx,
    const float* __restrict__ W, const float* __restrict__ bias,
    float* __restrict__ out)
{
    __shared__ __align__(16) unsigned short As[128][72];
    __shared__ __align__(16) unsigned short Bs[64][72];
    const int tid = threadIdx.x;
    const int c0  = blockIdx.x << 6;
    const int r0  = blockIdx.y << 7;
    const int w   = tid >> 6, lane = tid & 63, c = lane & 15, quad = lane >> 4;
    floatx4 acc[2][4] = {};
    for (int k0 = 0; k0 < E; k0 += 64) {
        const int h = k0 >> 6;
#pragma unroll
        for (int i = 0; i < 4; ++i) {
            const int idx = tid + (i << 8);
            const int r = idx >> 3, q = (idx & 7) << 3;
            const int rg = r0 + r, t = rg >> 4, b = rg & 15;
            *(int4*)&As[r][q] = *(const int4*)&ctx[((size_t)(b * H + h) * TGT + t) * HD + q];
        }
#pragma unroll
        for (int i = 0; i < 2; ++i) {
            const int idx = tid + (i << 8);
            const int r = idx >> 3, q = (idx & 7) << 3;
            const float4 f0 = *(const float4*)&W[(size_t)(c0 + r) * E + k0 + q];
            const float4 f1 = *(const float4*)&W[(size_t)(c0 + r) * E + k0 + q + 4];
            unsigned short o[8] = {f2bf(f0.x), f2bf(f0.y), f2bf(f0.z), f2bf(f0.w),
                                   f2bf(f1.x), f2bf(f1.y), f2bf(f1.z), f2bf(f1.w)};
            *(int4*)&Bs[r][q] = *(int4*)o;
        }
        __syncthreads();
#pragma unroll
        for (int kh = 0; kh < 2; ++kh) {
            short8 a0 = *(const short8*)&As[(w << 5) + c][(kh << 5) + (quad << 3)];
            short8 a1 = *(const short8*)&As[(w << 5) + 16 + c][(kh << 5) + (quad << 3)];
#pragma unroll
            for (int n = 0; n < 4; ++n) {
                short8 b = *(const short8*)&Bs[(n << 4) + c][(kh << 5) + (quad << 3)];
                acc[0][n] = __builtin_amdgcn_mfma_f32_16x16x32_bf16(a0, b, acc[0][n], 0, 0, 0);
                acc[1][n] = __builtin_amdgcn_mfma_f32_16x16x32_bf16(a1, b, acc[1][n], 0, 0, 0);
            }
        }
        __syncthreads();
    }
#pragma unroll
    for (int mt = 0; mt < 2; ++mt) {
#pragma unroll
        for (int reg = 0; reg < 4; ++reg) {
            const int rg = r0 + (w << 5) + (mt << 4) + (quad << 2) + reg;
#pragma unroll
            for (int n = 0; n < 4; ++n) {
                const int col = c0 + (n << 4) + c;
                out[(size_t)rg * E + col] = acc[mt][n][reg] + bias[col];
            }
        }
    }
}

extern "C" void kernel_launch(void* const* d_in, const int* in_sizes, int n_in,
                              void* d_out, int out_size, void* d_ws, size_t ws_size,
                              hipStream_t stream)
{
    const float* query  = (const float*)d_in[0];
    const float* key    = (const float*)d_in[1];
    const float* value  = (const float*)d_in[2];
    const float* ipw    = (const float*)d_in[3];
    const float* ipb    = (const float*)d_in[4];
    const float* bias_k = (const float*)d_in[5];
    const float* bias_v = (const float*)d_in[6];
    const float* opw    = (const float*)d_in[7];
    const float* opb    = (const float*)d_in[8];
    const int*   kpm    = (const int*)d_in[9];

    float* out  = (float*)d_out;
    float* attn = out + (size_t)TGT * NB * E;                 // 128*512*2049 fp32

    // V row-major scratch dies before attn_fused writes the attn region
    unsigned short* vbuf = (unsigned short*)attn;             // [bh][s][hd] bf16

    char* ws = (char*)d_ws;
    unsigned short* qbh   = (unsigned short*)ws;                       // [bh][t][hd]
    unsigned short* kbuf  = qbh   + (size_t)4194304;                   // [bh][S1P][hd]
    unsigned short* vtbuf = kbuf  + (size_t)17301504;                  // [bh][hd][S1P]
    unsigned short* ctx   = vtbuf + (size_t)17301504;                  // [bh][t][hd]

    proj_gemm<<<dim3(8, 64),  256, 0, stream>>>(query, ipw,           ipb,         qbh,  TGT, 0.125f);
    proj_gemm<<<dim3(8, 256), 256, 0, stream>>>(key,   ipw + 262144,  ipb + E,     kbuf, S1P, 1.0f);
    proj_gemm<<<dim3(8, 256), 256, 0, stream>>>(value, ipw + 524288,  ipb + 2 * E, vbuf, SRC, 1.0f);

    fill_bias<<<dim3(2300), 256, 0, stream>>>(bias_k, bias_v, kbuf, vtbuf);
    transpose_v<<<dim3(32, 128), 256, 0, stream>>>(vbuf, vtbuf);

    attn_fused<<<dim3(32, 128), 512, 0, stream>>>(qbh, kbuf, vtbuf, kpm, attn, ctx);
    outproj_gemm<<<dim3(8, 64), 256, 0, stream>>>(ctx, opw, opb, out);
}

// Round 5
// 1122.626 us; speedup vs baseline: 1.0344x; 1.0344x over previous
//
#include <hip/hip_runtime.h>
#include <hip/hip_bf16.h>

#define E    512
#define H    8
#define HD   64
#define TGT  512
#define SRC  2048
#define S1   2049
#define S1P  2112     // padded source length (33 chunks of 64)
#define NB   16
#define BH   128
#define NCH  33
#define PW   2120     // P row stride in shorts: 4240 B = 16B-aligned, bank-uniform

typedef __attribute__((ext_vector_type(8))) short short8;
typedef __attribute__((ext_vector_type(4))) float floatx4;

__device__ __forceinline__ unsigned short f2bf(float x) {
    unsigned u = __float_as_uint(x);
    u = (u + 0x7FFF + ((u >> 16) & 1)) >> 16;   // round-to-nearest-even
    return (unsigned short)u;
}

// pack 8 fp32 -> 8 bf16 (RNE) via compiler-fused v_cvt_pk_bf16_f32
__device__ __forceinline__ int4 cvt8(const float4 f0, const float4 f1) {
    __hip_bfloat162 o[4];
    o[0] = __float22bfloat162_rn({f0.x, f0.y});
    o[1] = __float22bfloat162_rn({f0.z, f0.w});
    o[2] = __float22bfloat162_rn({f1.x, f1.y});
    o[3] = __float22bfloat162_rn({f1.z, f1.w});
    return *(int4*)o;
}

// ---------------------------------------------------------------------------
// in-projection: Y = (X @ W^T + bias) * scale, fp32 inputs converted to bf16
// in-register during global->LDS staging (packed cvt_pk, ~1/8 the VALU of a
// scalar bit-twiddle). output bf16 in [b*H+h][row][hd]
// ---------------------------------------------------------------------------
__global__ __launch_bounds__(256) void proj_gemm(const float* __restrict__ X,
    const float* __restrict__ W, const float* __restrict__ bias,
    unsigned short* __restrict__ Y, const int ld, const float scale)
{
    __shared__ __align__(16) unsigned short As[128][72];
    __shared__ __align__(16) unsigned short Bs[64][72];
    const int tid  = threadIdx.x;
    const int c0   = blockIdx.x << 6;
    const int r0   = blockIdx.y << 7;
    const int w    = tid >> 6, lane = tid & 63, c = lane & 15, quad = lane >> 4;
    floatx4 acc[2][4] = {};
    for (int k0 = 0; k0 < E; k0 += 64) {
#pragma unroll
        for (int i = 0; i < 4; ++i) {
            const int idx = tid + (i << 8);
            const int r = idx >> 3, q = (idx & 7) << 3;
            const float4 f0 = *(const float4*)&X[(size_t)(r0 + r) * E + k0 + q];
            const float4 f1 = *(const float4*)&X[(size_t)(r0 + r) * E + k0 + q + 4];
            *(int4*)&As[r][q] = cvt8(f0, f1);
        }
#pragma unroll
        for (int i = 0; i < 2; ++i) {
            const int idx = tid + (i << 8);
            const int r = idx >> 3, q = (idx & 7) << 3;
            const float4 f0 = *(const float4*)&W[(size_t)(c0 + r) * E + k0 + q];
            const float4 f1 = *(const float4*)&W[(size_t)(c0 + r) * E + k0 + q + 4];
            *(int4*)&Bs[r][q] = cvt8(f0, f1);
        }
        __syncthreads();
#pragma unroll
        for (int kh = 0; kh < 2; ++kh) {
            short8 a0 = *(const short8*)&As[(w << 5) + c][(kh << 5) + (quad << 3)];
            short8 a1 = *(const short8*)&As[(w << 5) + 16 + c][(kh << 5) + (quad << 3)];
#pragma unroll
            for (int n = 0; n < 4; ++n) {
                short8 b = *(const short8*)&Bs[(n << 4) + c][(kh << 5) + (quad << 3)];
                acc[0][n] = __builtin_amdgcn_mfma_f32_16x16x32_bf16(a0, b, acc[0][n], 0, 0, 0);
                acc[1][n] = __builtin_amdgcn_mfma_f32_16x16x32_bf16(a1, b, acc[1][n], 0, 0, 0);
            }
        }
        __syncthreads();
    }
#pragma unroll
    for (int mt = 0; mt < 2; ++mt) {
#pragma unroll
        for (int reg = 0; reg < 4; ++reg) {
            const int rg = r0 + (w << 5) + (mt << 4) + (quad << 2) + reg;
            const int t = rg >> 4, b = rg & 15;
#pragma unroll
            for (int n = 0; n < 4; ++n) {
                const int col = c0 + (n << 4) + c;
                const int h = col >> 6, hd = col & 63;
                const float v = (acc[mt][n][reg] + bias[col]) * scale;
                Y[((size_t)(b * H + h) * ld + t) * HD + hd] = f2bf(v);
            }
        }
    }
}

// ---------------------------------------------------------------------------
// bias columns + pad-tail zeroing, fully parallel (one store per thread).
// ---------------------------------------------------------------------------
#define FB_BIAS  8192
#define FB_KPAD  64512                       // 128 bh * 504 int4 (63 rows * 64 hd)
#define FB_VPAD  516096                      // 128 bh * 64 hd * 63 s
__global__ __launch_bounds__(256) void fill_bias(const float* __restrict__ bk,
    const float* __restrict__ bv,
    unsigned short* __restrict__ kbuf, unsigned short* __restrict__ vtbuf)
{
    const int idx = blockIdx.x * 256 + threadIdx.x;
    if (idx < FB_BIAS) {
        const int bh = idx >> 6, hd = idx & 63, h = bh & 7;
        kbuf[((size_t)bh * S1P + SRC) * HD + hd] = f2bf(bk[h * HD + hd]);
        vtbuf[((size_t)bh * HD + hd) * S1P + SRC] = f2bf(bv[h * HD + hd]);
    } else if (idx < FB_BIAS + FB_KPAD) {
        const int i = idx - FB_BIAS;
        const int bh = i / 504, o = i % 504;
        const int4 z = {0, 0, 0, 0};
        ((int4*)&kbuf[((size_t)bh * S1P + S1) * HD])[o] = z;
    } else if (idx < FB_BIAS + FB_KPAD + FB_VPAD) {
        const int i = idx - FB_BIAS - FB_KPAD;
        const int bh = i / 4032, r = i % 4032;
        const int hd = r / 63, s = S1 + r % 63;
        vtbuf[((size_t)bh * HD + hd) * S1P + s] = 0;
    }
}

// vbuf [bh][s][hd] -> vtbuf [bh][hd][s]
__global__ __launch_bounds__(256) void transpose_v(const unsigned short* __restrict__ vbuf,
    unsigned short* __restrict__ vtbuf)
{
    __shared__ __align__(16) unsigned short T[64][72];
    const int tid = threadIdx.x;
    const int s0  = blockIdx.x << 6;
    const int bh  = blockIdx.y;
#pragma unroll
    for (int i = 0; i < 2; ++i) {
        const int idx = tid + (i << 8);
        const int s = idx >> 3, q = (idx & 7) << 3;
        *(int4*)&T[s][q] = *(const int4*)&vbuf[((size_t)bh * SRC + s0 + s) * HD + q];
    }
    __syncthreads();
#pragma unroll
    for (int i = 0; i < 2; ++i) {
        const int idx = tid + (i << 8);
        const int hd = idx >> 3, sq = (idx & 7) << 3;
        unsigned short tmp[8];
#pragma unroll
        for (int j = 0; j < 8; ++j) tmp[j] = T[sq + j][hd];
        *(int4*)&vtbuf[((size_t)bh * HD + hd) * S1P + s0 + sq] = *(int4*)tmp;
    }
}

// ---------------------------------------------------------------------------
// Fused single-pass attention, 512 threads / 8 waves / 2 blocks per CU.
//  - XCD-chunked block swizzle (FETCH 275 -> 88 MB, kept)
//  - phase 1: rolled dynamic loop, prefetch depth 1 (the R3 schedule; the
//    static unroll let the compiler sink loads -> VGPR 64, lost the overlap)
//  - phase 3a: PV split (4 hd-slices x 2 K-halves), V prefetch depth 4
//  - phase 3b: paired b32 P reads, 8-way wave-parallel fp32 attn stores
// ---------------------------------------------------------------------------
__global__ __launch_bounds__(512, 4) void attn_fused(
    const unsigned short* __restrict__ qbh,
    const unsigned short* __restrict__ kbuf,
    const unsigned short* __restrict__ vtbuf,
    const int* __restrict__ kpm,
    float* __restrict__ attn, unsigned short* __restrict__ ctx)
{
    __shared__ __align__(16) unsigned short P[16][PW];   // 67.84 KB
    __shared__ float cpart[16][68];                      // 4.25 KB
    __shared__ float sums[8][16];
    __shared__ float linv[16];
    const int tid  = threadIdx.x;
    const int orig = blockIdx.y * 32 + blockIdx.x;       // 0..4095
    const int swz  = (orig & 7) * 512 + (orig >> 3);     // XCD-chunked, bijective
    const int t0   = (swz & 31) << 4;
    const int bh   = swz >> 5;
    const int bb   = bh >> 3;
    const int w = tid >> 6, lane = tid & 63, c = lane & 15, quad = lane >> 4;

    // Q A-fragments for this block's 16 rows (same for every wave)
    const unsigned short* qr = &qbh[((size_t)bh * TGT + t0 + c) * HD + (quad << 3)];
    short8 qa0 = *(const short8*)qr;
    short8 qa1 = *(const short8*)(qr + 32);

#define LOADK(D0, D1, M, CH) do {                                               \
        const unsigned short* kb_ = &kbuf[((size_t)bh * S1P + ((CH) << 6)) * HD]; \
        _Pragma("unroll")                                                       \
        for (int n_ = 0; n_ < 4; ++n_) {                                        \
            const unsigned short* kr_ = kb_ + ((n_ << 4) + c) * HD + (quad << 3); \
            D0[n_] = *(const short8*)kr_;                                       \
            D1[n_] = *(const short8*)(kr_ + 32);                                \
        }                                                                       \
        _Pragma("unroll")                                                       \
        for (int n_ = 0; n_ < 4; ++n_) {                                        \
            const int s_ = ((CH) << 6) + (n_ << 4) + c;                         \
            M[n_] = (s_ < SRC) ? (kpm[bb * SRC + s_] ? 3e38f : 0.f)             \
                               : ((s_ == SRC) ? 0.f : 3e38f);                   \
        }                                                                       \
    } while (0)

#define QK_COMPUTE(CH, B0, B1, M) do {                                          \
        const int s0_ = (CH) << 6;                                              \
        floatx4 sc_[4] = {};                                                    \
        _Pragma("unroll")                                                       \
        for (int n_ = 0; n_ < 4; ++n_) {                                        \
            sc_[n_] = __builtin_amdgcn_mfma_f32_16x16x32_bf16(qa0, B0[n_], sc_[n_], 0, 0, 0); \
            sc_[n_] = __builtin_amdgcn_mfma_f32_16x16x32_bf16(qa1, B1[n_], sc_[n_], 0, 0, 0); \
        }                                                                       \
        _Pragma("unroll")                                                       \
        for (int n_ = 0; n_ < 4; ++n_) {                                        \
            _Pragma("unroll")                                                   \
            for (int rg_ = 0; rg_ < 4; ++rg_) {                                 \
                const float p_ = __expf(sc_[n_][rg_] - M[n_]);                  \
                rs[rg_] += p_;                                                  \
                P[(quad << 2) + rg_][s0_ + (n_ << 4) + c] = f2bf(p_);           \
            }                                                                   \
        }                                                                       \
    } while (0)

    // ---- phase 1: QK^T + exp, 33 chunks over 8 waves, prefetch depth 1 ----
    float rs[4] = {0.f, 0.f, 0.f, 0.f};
    short8 kb0[4], kb1[4];
    float mk[4];
    LOADK(kb0, kb1, mk, w);
    int ch;
    for (ch = w; ch + 8 < NCH; ch += 8) {
        short8 nb0[4], nb1[4];
        float nm[4];
        LOADK(nb0, nb1, nm, ch + 8);
        QK_COMPUTE(ch, kb0, kb1, mk);
#pragma unroll
        for (int n = 0; n < 4; ++n) { kb0[n] = nb0[n]; kb1[n] = nb1[n]; mk[n] = nm[n]; }
    }
    QK_COMPUTE(ch, kb0, kb1, mk);

    // ---- phase 2: row-sum reduction (over c lanes, then over 8 waves) ----
#pragma unroll
    for (int reg = 0; reg < 4; ++reg) {
        float v = rs[reg];
        v += __shfl_xor(v, 1); v += __shfl_xor(v, 2);
        v += __shfl_xor(v, 4); v += __shfl_xor(v, 8);
        rs[reg] = v;
    }
    if (c == 0) {
#pragma unroll
        for (int reg = 0; reg < 4; ++reg)
            sums[w][(quad << 2) + reg] = rs[reg];
    }
    __syncthreads();
    if (tid < 16) {
        float s = 0.f;
#pragma unroll
        for (int i = 0; i < 8; ++i) s += sums[i][tid];
        linv[tid] = 1.0f / s;
    }
    __syncthreads();

    // ---- phase 3a: PV. wave -> (hd-slice hs, K-half kh2); 33 units of 32
    // columns per half; V prefetch depth 4, tail unit loaded first. ----
    const int hs = w & 3, kh2 = w >> 2;
    const int base = kh2 * 1056;
    const unsigned short* vrow = &vtbuf[((size_t)bh * HD + (hs << 4) + c) * S1P + base];
#define LV(U) (*(const short8*)&vrow[((U) << 5) + (quad << 3)])
#define LP(U) (*(const short8*)&P[c][base + ((U) << 5) + (quad << 3)])
    floatx4 ca0 = {}, ca1 = {};
    short8 vt = LV(32);
    short8 v0 = LV(0), v1 = LV(1), v2 = LV(2), v3 = LV(3);
#pragma unroll
    for (int u = 0; u < 32; u += 4) {
        ca0 = __builtin_amdgcn_mfma_f32_16x16x32_bf16(LP(u),     v0, ca0, 0, 0, 0);
        ca1 = __builtin_amdgcn_mfma_f32_16x16x32_bf16(LP(u + 1), v1, ca1, 0, 0, 0);
        if (u < 28) { v0 = LV(u + 4); v1 = LV(u + 5); }
        ca0 = __builtin_amdgcn_mfma_f32_16x16x32_bf16(LP(u + 2), v2, ca0, 0, 0, 0);
        ca1 = __builtin_amdgcn_mfma_f32_16x16x32_bf16(LP(u + 3), v3, ca1, 0, 0, 0);
        if (u < 28) { v2 = LV(u + 6); v3 = LV(u + 7); }
    }
    ca0 = __builtin_amdgcn_mfma_f32_16x16x32_bf16(LP(32), vt, ca0, 0, 0, 0);
    if (kh2 == 1) {
#pragma unroll
        for (int reg = 0; reg < 4; ++reg)
            cpart[(quad << 2) + reg][(hs << 4) + c] = ca0[reg] + ca1[reg];
    }
    __syncthreads();
    if (kh2 == 0) {
#pragma unroll
        for (int reg = 0; reg < 4; ++reg) {
            const int row = (quad << 2) + reg;
            const float v = (ca0[reg] + ca1[reg] + cpart[row][(hs << 4) + c]) * linv[row];
            ctx[((size_t)bh * TGT + t0 + row) * HD + (hs << 4) + c] = f2bf(v);
        }
    }

    // ---- phase 3b: normalized fp32 attn stores. 16 pairs of 64-col chunks
    // over 8 waves; each lane reads 2 P values per b32 LDS read. ----
    for (int p = w; p < 16; p += 8) {
        const int s0 = p << 7;
#pragma unroll
        for (int r = 0; r < 16; ++r) {
            const unsigned pk = *(const unsigned*)&P[r][s0 + (lane << 1)];
            const float li = linv[r];
            const size_t a = ((size_t)bh * TGT + t0 + r) * S1 + s0 + (lane << 1);
            attn[a]     = __uint_as_float((pk & 0xFFFFu) << 16) * li;
            attn[a + 1] = __uint_as_float(pk & 0xFFFF0000u) * li;
        }
    }
    if (w == 7 && lane < 16) {   // last real column s == 2048
        const float p = __uint_as_float((unsigned)P[lane][2048] << 16) * linv[lane];
        attn[((size_t)bh * TGT + t0 + lane) * S1 + 2048] = p;
    }
#undef LOADK
#undef QK_COMPUTE
#undef LV
#undef LP
}

// ---------------------------------------------------------------------------
// out-projection: out[r][e] = ctx_row(r) . W[e][:] + bias[e]  (fp32 out)
// ctx is bf16; W is fp32 converted during staging (packed cvt_pk).
// ---------------------------------------------------------------------------
__global__ __launch_bounds__(256) void outproj_gemm(const unsigned short* __restrict__ ctx,
    const float* __restrict__ W, const float* __restrict__ bias,
    float* __restrict__ out)
{
    __shared__ __align__(16) unsigned short As[128][72];
    __shared__ __align__(16) unsigned short Bs[64][72];
    const int tid = threadIdx.x;
    const int c0  = blockIdx.x << 6;
    const int r0  = blockIdx.y << 7;
    const int w   = tid >> 6, lane = tid & 63, c = lane & 15, quad = lane >> 4;
    floatx4 acc[2][4] = {};
    for (int k0 = 0; k0 < E; k0 += 64) {
        const int h = k0 >> 6;
#pragma unroll
        for (int i = 0; i < 4; ++i) {
            const int idx = tid + (i << 8);
            const int r = idx >> 3, q = (idx & 7) << 3;
            const int rg = r0 + r, t = rg >> 4, b = rg & 15;
            *(int4*)&As[r][q] = *(const int4*)&ctx[((size_t)(b * H + h) * TGT + t) * HD + q];
        }
#pragma unroll
        for (int i = 0; i < 2; ++i) {
            const int idx = tid + (i << 8);
            const int r = idx >> 3, q = (idx & 7) << 3;
            const float4 f0 = *(const float4*)&W[(size_t)(c0 + r) * E + k0 + q];
            const float4 f1 = *(const float4*)&W[(size_t)(c0 + r) * E + k0 + q + 4];
            *(int4*)&Bs[r][q] = cvt8(f0, f1);
        }
        __syncthreads();
#pragma unroll
        for (int kh = 0; kh < 2; ++kh) {
            short8 a0 = *(const short8*)&As[(w << 5) + c][(kh << 5) + (quad << 3)];
            short8 a1 = *(const short8*)&As[(w << 5) + 16 + c][(kh << 5) + (quad << 3)];
#pragma unroll
            for (int n = 0; n < 4; ++n) {
                short8 b = *(const short8*)&Bs[(n << 4) + c][(kh << 5) + (quad << 3)];
                acc[0][n] = __builtin_amdgcn_mfma_f32_16x16x32_bf16(a0, b, acc[0][n], 0, 0, 0);
                acc[1][n] = __builtin_amdgcn_mfma_f32_16x16x32_bf16(a1, b, acc[1][n], 0, 0, 0);
            }
        }
        __syncthreads();
    }
#pragma unroll
    for (int mt = 0; mt < 2; ++mt) {
#pragma unroll
        for (int reg = 0; reg < 4; ++reg) {
            const int rg = r0 + (w << 5) + (mt << 4) + (quad << 2) + reg;
#pragma unroll
            for (int n = 0; n < 4; ++n) {
                const int col = c0 + (n << 4) + c;
                out[(size_t)rg * E + col] = acc[mt][n][reg] + bias[col];
            }
        }
    }
}

extern "C" void kernel_launch(void* const* d_in, const int* in_sizes, int n_in,
                              void* d_out, int out_size, void* d_ws, size_t ws_size,
                              hipStream_t stream)
{
    const float* query  = (const float*)d_in[0];
    const float* key    = (const float*)d_in[1];
    const float* value  = (const float*)d_in[2];
    const float* ipw    = (const float*)d_in[3];
    const float* ipb    = (const float*)d_in[4];
    const float* bias_k = (const float*)d_in[5];
    const float* bias_v = (const float*)d_in[6];
    const float* opw    = (const float*)d_in[7];
    const float* opb    = (const float*)d_in[8];
    const int*   kpm    = (const int*)d_in[9];

    float* out  = (float*)d_out;
    float* attn = out + (size_t)TGT * NB * E;                 // 128*512*2049 fp32

    // V row-major scratch dies before attn_fused writes the attn region
    unsigned short* vbuf = (unsigned short*)attn;             // [bh][s][hd] bf16

    char* ws = (char*)d_ws;
    unsigned short* qbh   = (unsigned short*)ws;                       // [bh][t][hd]
    unsigned short* kbuf  = qbh   + (size_t)4194304;                   // [bh][S1P][hd]
    unsigned short* vtbuf = kbuf  + (size_t)17301504;                  // [bh][hd][S1P]
    unsigned short* ctx   = vtbuf + (size_t)17301504;                  // [bh][t][hd]

    proj_gemm<<<dim3(8, 64),  256, 0, stream>>>(query, ipw,           ipb,         qbh,  TGT, 0.125f);
    proj_gemm<<<dim3(8, 256), 256, 0, stream>>>(key,   ipw + 262144,  ipb + E,     kbuf, S1P, 1.0f);
    proj_gemm<<<dim3(8, 256), 256, 0, stream>>>(value, ipw + 524288,  ipb + 2 * E, vbuf, SRC, 1.0f);

    fill_bias<<<dim3(2300), 256, 0, stream>>>(bias_k, bias_v, kbuf, vtbuf);
    transpose_v<<<dim3(32, 128), 256, 0, stream>>>(vbuf, vtbuf);

    attn_fused<<<dim3(32, 128), 512, 0, stream>>>(qbh, kbuf, vtbuf, kpm, attn, ctx);
    outproj_gemm<<<dim3(8, 64), 256, 0, stream>>>(ctx, opw, opb, out);
}

// Round 6
// 1119.092 us; speedup vs baseline: 1.0376x; 1.0032x over previous
//
#include <hip/hip_runtime.h>
#include <hip/hip_bf16.h>

#define E    512
#define H    8
#define HD   64
#define TGT  512
#define SRC  2048
#define S1   2049
#define S1P  2112     // padded source length (33 chunks of 64)
#define NB   16
#define BH   128
#define NCH  33
#define PW   2120     // P row stride in shorts: 4240 B = 16B-aligned, bank-uniform

typedef __attribute__((ext_vector_type(8))) short short8;
typedef __attribute__((ext_vector_type(4))) float floatx4;

__device__ __forceinline__ unsigned short f2bf(float x) {
    unsigned u = __float_as_uint(x);
    u = (u + 0x7FFF + ((u >> 16) & 1)) >> 16;   // round-to-nearest-even
    return (unsigned short)u;
}

// single fp32 -> bf16 RNE via hardware cvt (1 instr, not 4)
__device__ __forceinline__ unsigned short f2bf1(float x) {
    __hip_bfloat16 h = __float2bfloat16(x);
    return *(unsigned short*)&h;
}

// pack 8 fp32 -> 8 bf16 (RNE) via compiler-fused v_cvt_pk_bf16_f32
__device__ __forceinline__ int4 cvt8(const float4 f0, const float4 f1) {
    __hip_bfloat162 o[4];
    o[0] = __float22bfloat162_rn({f0.x, f0.y});
    o[1] = __float22bfloat162_rn({f0.z, f0.w});
    o[2] = __float22bfloat162_rn({f1.x, f1.y});
    o[3] = __float22bfloat162_rn({f1.z, f1.w});
    return *(int4*)o;
}

// ---------------------------------------------------------------------------
// in-projection: Y = (X @ W^T + bias) * scale, fp32 inputs converted to bf16
// in-register during global->LDS staging. output bf16 in [b*H+h][row][hd]
// ---------------------------------------------------------------------------
__global__ __launch_bounds__(256) void proj_gemm(const float* __restrict__ X,
    const float* __restrict__ W, const float* __restrict__ bias,
    unsigned short* __restrict__ Y, const int ld, const float scale)
{
    __shared__ __align__(16) unsigned short As[128][72];
    __shared__ __align__(16) unsigned short Bs[64][72];
    const int tid  = threadIdx.x;
    const int c0   = blockIdx.x << 6;
    const int r0   = blockIdx.y << 7;
    const int w    = tid >> 6, lane = tid & 63, c = lane & 15, quad = lane >> 4;
    floatx4 acc[2][4] = {};
    for (int k0 = 0; k0 < E; k0 += 64) {
#pragma unroll
        for (int i = 0; i < 4; ++i) {
            const int idx = tid + (i << 8);
            const int r = idx >> 3, q = (idx & 7) << 3;
            const float4 f0 = *(const float4*)&X[(size_t)(r0 + r) * E + k0 + q];
            const float4 f1 = *(const float4*)&X[(size_t)(r0 + r) * E + k0 + q + 4];
            *(int4*)&As[r][q] = cvt8(f0, f1);
        }
#pragma unroll
        for (int i = 0; i < 2; ++i) {
            const int idx = tid + (i << 8);
            const int r = idx >> 3, q = (idx & 7) << 3;
            const float4 f0 = *(const float4*)&W[(size_t)(c0 + r) * E + k0 + q];
            const float4 f1 = *(const float4*)&W[(size_t)(c0 + r) * E + k0 + q + 4];
            *(int4*)&Bs[r][q] = cvt8(f0, f1);
        }
        __syncthreads();
#pragma unroll
        for (int kh = 0; kh < 2; ++kh) {
            short8 a0 = *(const short8*)&As[(w << 5) + c][(kh << 5) + (quad << 3)];
            short8 a1 = *(const short8*)&As[(w << 5) + 16 + c][(kh << 5) + (quad << 3)];
#pragma unroll
            for (int n = 0; n < 4; ++n) {
                short8 b = *(const short8*)&Bs[(n << 4) + c][(kh << 5) + (quad << 3)];
                acc[0][n] = __builtin_amdgcn_mfma_f32_16x16x32_bf16(a0, b, acc[0][n], 0, 0, 0);
                acc[1][n] = __builtin_amdgcn_mfma_f32_16x16x32_bf16(a1, b, acc[1][n], 0, 0, 0);
            }
        }
        __syncthreads();
    }
#pragma unroll
    for (int mt = 0; mt < 2; ++mt) {
#pragma unroll
        for (int reg = 0; reg < 4; ++reg) {
            const int rg = r0 + (w << 5) + (mt << 4) + (quad << 2) + reg;
            const int t = rg >> 4, b = rg & 15;
#pragma unroll
            for (int n = 0; n < 4; ++n) {
                const int col = c0 + (n << 4) + c;
                const int h = col >> 6, hd = col & 63;
                const float v = (acc[mt][n][reg] + bias[col]) * scale;
                Y[((size_t)(b * H + h) * ld + t) * HD + hd] = f2bf(v);
            }
        }
    }
}

// ---------------------------------------------------------------------------
// bias columns + pad-tail zeroing, fully parallel (one store per thread).
// ---------------------------------------------------------------------------
#define FB_BIAS  8192
#define FB_KPAD  64512                       // 128 bh * 504 int4 (63 rows * 64 hd)
#define FB_VPAD  516096                      // 128 bh * 64 hd * 63 s
__global__ __launch_bounds__(256) void fill_bias(const float* __restrict__ bk,
    const float* __restrict__ bv,
    unsigned short* __restrict__ kbuf, unsigned short* __restrict__ vtbuf)
{
    const int idx = blockIdx.x * 256 + threadIdx.x;
    if (idx < FB_BIAS) {
        const int bh = idx >> 6, hd = idx & 63, h = bh & 7;
        kbuf[((size_t)bh * S1P + SRC) * HD + hd] = f2bf(bk[h * HD + hd]);
        vtbuf[((size_t)bh * HD + hd) * S1P + SRC] = f2bf(bv[h * HD + hd]);
    } else if (idx < FB_BIAS + FB_KPAD) {
        const int i = idx - FB_BIAS;
        const int bh = i / 504, o = i % 504;
        const int4 z = {0, 0, 0, 0};
        ((int4*)&kbuf[((size_t)bh * S1P + S1) * HD])[o] = z;
    } else if (idx < FB_BIAS + FB_KPAD + FB_VPAD) {
        const int i = idx - FB_BIAS - FB_KPAD;
        const int bh = i / 4032, r = i % 4032;
        const int hd = r / 63, s = S1 + r % 63;
        vtbuf[((size_t)bh * HD + hd) * S1P + s] = 0;
    }
}

// vbuf [bh][s][hd] -> vtbuf [bh][hd][s]
__global__ __launch_bounds__(256) void transpose_v(const unsigned short* __restrict__ vbuf,
    unsigned short* __restrict__ vtbuf)
{
    __shared__ __align__(16) unsigned short T[64][72];
    const int tid = threadIdx.x;
    const int s0  = blockIdx.x << 6;
    const int bh  = blockIdx.y;
#pragma unroll
    for (int i = 0; i < 2; ++i) {
        const int idx = tid + (i << 8);
        const int s = idx >> 3, q = (idx & 7) << 3;
        *(int4*)&T[s][q] = *(const int4*)&vbuf[((size_t)bh * SRC + s0 + s) * HD + q];
    }
    __syncthreads();
#pragma unroll
    for (int i = 0; i < 2; ++i) {
        const int idx = tid + (i << 8);
        const int hd = idx >> 3, sq = (idx & 7) << 3;
        unsigned short tmp[8];
#pragma unroll
        for (int j = 0; j < 8; ++j) tmp[j] = T[sq + j][hd];
        *(int4*)&vtbuf[((size_t)bh * HD + hd) * S1P + s0 + sq] = *(int4*)tmp;
    }
}

// ---------------------------------------------------------------------------
// Fused single-pass attention, 1024 threads / 16 waves per block.
// Same 73 KB LDS tile -> still 2 blocks/CU, but 32 waves/CU (8/SIMD, the
// occupancy cap). Counters showed a pure latency-stall kernel (Mfma 4%,
// VALU 15%, HBM 20%, Occ 43%); ILP attempts were defeated by the register
// allocator (VGPR 52), so double TLP at the same footprint instead.
//  - phase 1: 33 chunks over 16 waves, rolled prefetch depth 1
//  - phase 3: wave role-split: waves 0-7 PV (setprio around MFMA cluster),
//    waves 8-15 stream the normalized fp32 attn stores concurrently
// ---------------------------------------------------------------------------
__global__ __launch_bounds__(1024, 8) void attn_fused(
    const unsigned short* __restrict__ qbh,
    const unsigned short* __restrict__ kbuf,
    const unsigned short* __restrict__ vtbuf,
    const int* __restrict__ kpm,
    float* __restrict__ attn, unsigned short* __restrict__ ctx)
{
    __shared__ __align__(16) unsigned short P[16][PW];   // 67.84 KB
    __shared__ float cpart[16][68];                      // 4.25 KB
    __shared__ float sums[16][16];                       // 1 KB
    __shared__ float linv[16];
    const int tid  = threadIdx.x;
    const int orig = blockIdx.y * 32 + blockIdx.x;       // 0..4095
    const int swz  = (orig & 7) * 512 + (orig >> 3);     // XCD-chunked, bijective
    const int t0   = (swz & 31) << 4;
    const int bh   = swz >> 5;
    const int bb   = bh >> 3;
    const int w = tid >> 6, lane = tid & 63, c = lane & 15, quad = lane >> 4;

    // Q A-fragments for this block's 16 rows (same for every wave)
    const unsigned short* qr = &qbh[((size_t)bh * TGT + t0 + c) * HD + (quad << 3)];
    short8 qa0 = *(const short8*)qr;
    short8 qa1 = *(const short8*)(qr + 32);

#define LOADK(D0, D1, M, CH) do {                                               \
        const unsigned short* kb_ = &kbuf[((size_t)bh * S1P + ((CH) << 6)) * HD]; \
        _Pragma("unroll")                                                       \
        for (int n_ = 0; n_ < 4; ++n_) {                                        \
            const unsigned short* kr_ = kb_ + ((n_ << 4) + c) * HD + (quad << 3); \
            D0[n_] = *(const short8*)kr_;                                       \
            D1[n_] = *(const short8*)(kr_ + 32);                                \
        }                                                                       \
        _Pragma("unroll")                                                       \
        for (int n_ = 0; n_ < 4; ++n_) {                                        \
            const int s_ = ((CH) << 6) + (n_ << 4) + c;                         \
            M[n_] = (s_ < SRC) ? (kpm[bb * SRC + s_] ? 3e38f : 0.f)             \
                               : ((s_ == SRC) ? 0.f : 3e38f);                   \
        }                                                                       \
    } while (0)

#define QK_COMPUTE(CH, B0, B1, M) do {                                          \
        const int s0_ = (CH) << 6;                                              \
        floatx4 sc_[4] = {};                                                    \
        _Pragma("unroll")                                                       \
        for (int n_ = 0; n_ < 4; ++n_) {                                        \
            sc_[n_] = __builtin_amdgcn_mfma_f32_16x16x32_bf16(qa0, B0[n_], sc_[n_], 0, 0, 0); \
            sc_[n_] = __builtin_amdgcn_mfma_f32_16x16x32_bf16(qa1, B1[n_], sc_[n_], 0, 0, 0); \
        }                                                                       \
        _Pragma("unroll")                                                       \
        for (int n_ = 0; n_ < 4; ++n_) {                                        \
            _Pragma("unroll")                                                   \
            for (int rg_ = 0; rg_ < 4; ++rg_) {                                 \
                const float p_ = __expf(sc_[n_][rg_] - M[n_]);                  \
                rs[rg_] += p_;                                                  \
                P[(quad << 2) + rg_][s0_ + (n_ << 4) + c] = f2bf1(p_);          \
            }                                                                   \
        }                                                                       \
    } while (0)

    // ---- phase 1: QK^T + exp, 33 chunks over 16 waves, prefetch depth 1 ----
    float rs[4] = {0.f, 0.f, 0.f, 0.f};
    short8 kb0[4], kb1[4];
    float mk[4];
    LOADK(kb0, kb1, mk, w);
    int ch;
    for (ch = w; ch + 16 < NCH; ch += 16) {
        short8 nb0[4], nb1[4];
        float nm[4];
        LOADK(nb0, nb1, nm, ch + 16);
        QK_COMPUTE(ch, kb0, kb1, mk);
#pragma unroll
        for (int n = 0; n < 4; ++n) { kb0[n] = nb0[n]; kb1[n] = nb1[n]; mk[n] = nm[n]; }
    }
    QK_COMPUTE(ch, kb0, kb1, mk);

    // ---- phase 2: row-sum reduction (over c lanes, then over 16 waves) ----
#pragma unroll
    for (int reg = 0; reg < 4; ++reg) {
        float v = rs[reg];
        v += __shfl_xor(v, 1); v += __shfl_xor(v, 2);
        v += __shfl_xor(v, 4); v += __shfl_xor(v, 8);
        rs[reg] = v;
    }
    if (c == 0) {
#pragma unroll
        for (int reg = 0; reg < 4; ++reg)
            sums[w][(quad << 2) + reg] = rs[reg];
    }
    __syncthreads();
    if (tid < 16) {
        float s = 0.f;
#pragma unroll
        for (int i = 0; i < 16; ++i) s += sums[i][tid];
        linv[tid] = 1.0f / s;
    }
    __syncthreads();

    // ---- phase 3: role-split. waves 0-7: PV; waves 8-15: attn stores. ----
#define STORE_PAIR(PP) do {                                                     \
        const int s0_ = (PP) << 7;                                              \
        _Pragma("unroll")                                                       \
        for (int r_ = 0; r_ < 16; ++r_) {                                       \
            const unsigned pk_ = *(const unsigned*)&P[r_][s0_ + (lane << 1)];   \
            const float li_ = linv[r_];                                         \
            const size_t a_ = ((size_t)bh * TGT + t0 + r_) * S1 + s0_ + (lane << 1); \
            attn[a_]     = __uint_as_float((pk_ & 0xFFFFu) << 16) * li_;        \
            attn[a_ + 1] = __uint_as_float(pk_ & 0xFFFF0000u) * li_;            \
        }                                                                       \
    } while (0)

    const int hs = w & 3, kh2 = (w >> 2) & 1;
    floatx4 ca0 = {}, ca1 = {};
    if (w < 8) {
        // PV: wave -> (hd-slice hs, K-half kh2); 33 units of 32 cols per half
        const int base = kh2 * 1056;
        const unsigned short* vrow =
            &vtbuf[((size_t)bh * HD + (hs << 4) + c) * S1P + base];
#define LV(U) (*(const short8*)&vrow[((U) << 5) + (quad << 3)])
#define LP(U) (*(const short8*)&P[c][base + ((U) << 5) + (quad << 3)])
        short8 vt = LV(32);
        short8 v0 = LV(0), v1 = LV(1), v2 = LV(2), v3 = LV(3);
        __builtin_amdgcn_s_setprio(1);
#pragma unroll
        for (int u = 0; u < 32; u += 4) {
            ca0 = __builtin_amdgcn_mfma_f32_16x16x32_bf16(LP(u),     v0, ca0, 0, 0, 0);
            ca1 = __builtin_amdgcn_mfma_f32_16x16x32_bf16(LP(u + 1), v1, ca1, 0, 0, 0);
            if (u < 28) { v0 = LV(u + 4); v1 = LV(u + 5); }
            ca0 = __builtin_amdgcn_mfma_f32_16x16x32_bf16(LP(u + 2), v2, ca0, 0, 0, 0);
            ca1 = __builtin_amdgcn_mfma_f32_16x16x32_bf16(LP(u + 3), v3, ca1, 0, 0, 0);
            if (u < 28) { v2 = LV(u + 6); v3 = LV(u + 7); }
        }
        ca0 = __builtin_amdgcn_mfma_f32_16x16x32_bf16(LP(32), vt, ca0, 0, 0, 0);
        __builtin_amdgcn_s_setprio(0);
        if (kh2 == 1) {
#pragma unroll
            for (int reg = 0; reg < 4; ++reg)
                cpart[(quad << 2) + reg][(hs << 4) + c] = ca0[reg] + ca1[reg];
        }
#undef LV
#undef LP
    } else {
        STORE_PAIR(w - 8);                   // attn cols [128*(w-8), +128)
    }
    __syncthreads();
    if (w < 8) {
        if (kh2 == 0) {
#pragma unroll
            for (int reg = 0; reg < 4; ++reg) {
                const int row = (quad << 2) + reg;
                const float v =
                    (ca0[reg] + ca1[reg] + cpart[row][(hs << 4) + c]) * linv[row];
                ctx[((size_t)bh * TGT + t0 + row) * HD + (hs << 4) + c] = f2bf1(v);
            }
        }
    } else {
        STORE_PAIR(w);                       // attn cols [128*w, +128)
        if (w == 15 && lane < 16) {          // last real column s == 2048
            const float p =
                __uint_as_float((unsigned)P[lane][2048] << 16) * linv[lane];
            attn[((size_t)bh * TGT + t0 + lane) * S1 + 2048] = p;
        }
    }
#undef LOADK
#undef QK_COMPUTE
#undef STORE_PAIR
}

// ---------------------------------------------------------------------------
// out-projection: out[r][e] = ctx_row(r) . W[e][:] + bias[e]  (fp32 out)
// ctx is bf16; W is fp32 converted during staging (packed cvt_pk).
// ---------------------------------------------------------------------------
__global__ __launch_bounds__(256) void outproj_gemm(const unsigned short* __restrict__ ctx,
    const float* __restrict__ W, const float* __restrict__ bias,
    float* __restrict__ out)
{
    __shared__ __align__(16) unsigned short As[128][72];
    __shared__ __align__(16) unsigned short Bs[64][72];
    const int tid = threadIdx.x;
    const int c0  = blockIdx.x << 6;
    const int r0  = blockIdx.y << 7;
    const int w   = tid >> 6, lane = tid & 63, c = lane & 15, quad = lane >> 4;
    floatx4 acc[2][4] = {};
    for (int k0 = 0; k0 < E; k0 += 64) {
        const int h = k0 >> 6;
#pragma unroll
        for (int i = 0; i < 4; ++i) {
            const int idx = tid + (i << 8);
            const int r = idx >> 3, q = (idx & 7) << 3;
            const int rg = r0 + r, t = rg >> 4, b = rg & 15;
            *(int4*)&As[r][q] = *(const int4*)&ctx[((size_t)(b * H + h) * TGT + t) * HD + q];
        }
#pragma unroll
        for (int i = 0; i < 2; ++i) {
            const int idx = tid + (i << 8);
            const int r = idx >> 3, q = (idx & 7) << 3;
            const float4 f0 = *(const float4*)&W[(size_t)(c0 + r) * E + k0 + q];
            const float4 f1 = *(const float4*)&W[(size_t)(c0 + r) * E + k0 + q + 4];
            *(int4*)&Bs[r][q] = cvt8(f0, f1);
        }
        __syncthreads();
#pragma unroll
        for (int kh = 0; kh < 2; ++kh) {
            short8 a0 = *(const short8*)&As[(w << 5) + c][(kh << 5) + (quad << 3)];
            short8 a1 = *(const short8*)&As[(w << 5) + 16 + c][(kh << 5) + (quad << 3)];
#pragma unroll
            for (int n = 0; n < 4; ++n) {
                short8 b = *(const short8*)&Bs[(n << 4) + c][(kh << 5) + (quad << 3)];
                acc[0][n] = __builtin_amdgcn_mfma_f32_16x16x32_bf16(a0, b, acc[0][n], 0, 0, 0);
                acc[1][n] = __builtin_amdgcn_mfma_f32_16x16x32_bf16(a1, b, acc[1][n], 0, 0, 0);
            }
        }
        __syncthreads();
    }
#pragma unroll
    for (int mt = 0; mt < 2; ++mt) {
#pragma unroll
        for (int reg = 0; reg < 4; ++reg) {
            const int rg = r0 + (w << 5) + (mt << 4) + (quad << 2) + reg;
#pragma unroll
            for (int n = 0; n < 4; ++n) {
                const int col = c0 + (n << 4) + c;
                out[(size_t)rg * E + col] = acc[mt][n][reg] + bias[col];
            }
        }
    }
}

extern "C" void kernel_launch(void* const* d_in, const int* in_sizes, int n_in,
                              void* d_out, int out_size, void* d_ws, size_t ws_size,
                              hipStream_t stream)
{
    const float* query  = (const float*)d_in[0];
    const float* key    = (const float*)d_in[1];
    const float* value  = (const float*)d_in[2];
    const float* ipw    = (const float*)d_in[3];
    const float* ipb    = (const float*)d_in[4];
    const float* bias_k = (const float*)d_in[5];
    const float* bias_v = (const float*)d_in[6];
    const float* opw    = (const float*)d_in[7];
    const float* opb    = (const float*)d_in[8];
    const int*   kpm    = (const int*)d_in[9];

    float* out  = (float*)d_out;
    float* attn = out + (size_t)TGT * NB * E;                 // 128*512*2049 fp32

    // V row-major scratch dies before attn_fused writes the attn region
    unsigned short* vbuf = (unsigned short*)attn;             // [bh][s][hd] bf16

    char* ws = (char*)d_ws;
    unsigned short* qbh   = (unsigned short*)ws;                       // [bh][t][hd]
    unsigned short* kbuf  = qbh   + (size_t)4194304;                   // [bh][S1P][hd]
    unsigned short* vtbuf = kbuf  + (size_t)17301504;                  // [bh][hd][S1P]
    unsigned short* ctx   = vtbuf + (size_t)17301504;                  // [bh][t][hd]

    proj_gemm<<<dim3(8, 64),  256, 0, stream>>>(query, ipw,           ipb,         qbh,  TGT, 0.125f);
    proj_gemm<<<dim3(8, 256), 256, 0, stream>>>(key,   ipw + 262144,  ipb + E,     kbuf, S1P, 1.0f);
    proj_gemm<<<dim3(8, 256), 256, 0, stream>>>(value, ipw + 524288,  ipb + 2 * E, vbuf, SRC, 1.0f);

    fill_bias<<<dim3(2300), 256, 0, stream>>>(bias_k, bias_v, kbuf, vtbuf);
    transpose_v<<<dim3(32, 128), 256, 0, stream>>>(vbuf, vtbuf);

    attn_fused<<<dim3(32, 128), 1024, 0, stream>>>(qbh, kbuf, vtbuf, kpm, attn, ctx);
    outproj_gemm<<<dim3(8, 64), 256, 0, stream>>>(ctx, opw, opb, out);
}

// Round 7
// 1075.139 us; speedup vs baseline: 1.0801x; 1.0409x over previous
//
#include <hip/hip_runtime.h>
#include <hip/hip_bf16.h>

#define E    512
#define H    8
#define HD   64
#define TGT  512
#define SRC  2048
#define S1   2049
#define S1P  2112     // padded source length (33 chunks of 64)
#define NB   16
#define BH   128
#define NCH  33
#define PW   2120     // P row stride in shorts: 4240 B = 16B-aligned, bank-uniform

typedef __attribute__((ext_vector_type(8))) short short8;
typedef __attribute__((ext_vector_type(4))) float floatx4;

__device__ __forceinline__ unsigned short f2bf(float x) {
    unsigned u = __float_as_uint(x);
    u = (u + 0x7FFF + ((u >> 16) & 1)) >> 16;   // round-to-nearest-even
    return (unsigned short)u;
}

// single fp32 -> bf16 RNE via hardware cvt
__device__ __forceinline__ unsigned short f2bf1(float x) {
    __hip_bfloat16 h = __float2bfloat16(x);
    return *(unsigned short*)&h;
}

// pack 8 fp32 -> 8 bf16 (RNE) via compiler-fused v_cvt_pk_bf16_f32
__device__ __forceinline__ int4 cvt8(const float4 f0, const float4 f1) {
    __hip_bfloat162 o[4];
    o[0] = __float22bfloat162_rn({f0.x, f0.y});
    o[1] = __float22bfloat162_rn({f0.z, f0.w});
    o[2] = __float22bfloat162_rn({f1.x, f1.y});
    o[3] = __float22bfloat162_rn({f1.z, f1.w});
    return *(int4*)o;
}

// ---------------------------------------------------------------------------
// fp32 -> bf16 conversion, 8 elements/thread (packed cvt_pk)
// ---------------------------------------------------------------------------
__global__ __launch_bounds__(256) void cvt_bf16(const float* __restrict__ src,
    unsigned short* __restrict__ dst, const int n8)
{
    const int i = blockIdx.x * 256 + threadIdx.x;
    if (i >= n8) return;
    const float4 f0 = ((const float4*)src)[(size_t)i * 2];
    const float4 f1 = ((const float4*)src)[(size_t)i * 2 + 1];
    ((int4*)dst)[i] = cvt8(f0, f1);
}

// ---------------------------------------------------------------------------
// in-projection: Y = (X @ W^T + bias) * scale, bf16 in, output bf16 in
// [b*H+h][row][hd]
// ---------------------------------------------------------------------------
__global__ __launch_bounds__(256) void proj_gemm(const unsigned short* __restrict__ X,
    const unsigned short* __restrict__ W, const float* __restrict__ bias,
    unsigned short* __restrict__ Y, const int ld, const float scale)
{
    __shared__ __align__(16) unsigned short As[128][72];
    __shared__ __align__(16) unsigned short Bs[64][72];
    const int tid  = threadIdx.x;
    const int c0   = blockIdx.x << 6;
    const int r0   = blockIdx.y << 7;
    const int w    = tid >> 6, lane = tid & 63, c = lane & 15, quad = lane >> 4;
    floatx4 acc[2][4] = {};
    for (int k0 = 0; k0 < E; k0 += 64) {
#pragma unroll
        for (int i = 0; i < 4; ++i) {
            const int idx = tid + (i << 8);
            const int r = idx >> 3, q = (idx & 7) << 3;
            *(int4*)&As[r][q] = *(const int4*)&X[(size_t)(r0 + r) * E + k0 + q];
        }
#pragma unroll
        for (int i = 0; i < 2; ++i) {
            const int idx = tid + (i << 8);
            const int r = idx >> 3, q = (idx & 7) << 3;
            *(int4*)&Bs[r][q] = *(const int4*)&W[(size_t)(c0 + r) * E + k0 + q];
        }
        __syncthreads();
#pragma unroll
        for (int kh = 0; kh < 2; ++kh) {
            short8 a0 = *(const short8*)&As[(w << 5) + c][(kh << 5) + (quad << 3)];
            short8 a1 = *(const short8*)&As[(w << 5) + 16 + c][(kh << 5) + (quad << 3)];
#pragma unroll
            for (int n = 0; n < 4; ++n) {
                short8 b = *(const short8*)&Bs[(n << 4) + c][(kh << 5) + (quad << 3)];
                acc[0][n] = __builtin_amdgcn_mfma_f32_16x16x32_bf16(a0, b, acc[0][n], 0, 0, 0);
                acc[1][n] = __builtin_amdgcn_mfma_f32_16x16x32_bf16(a1, b, acc[1][n], 0, 0, 0);
            }
        }
        __syncthreads();
    }
#pragma unroll
    for (int mt = 0; mt < 2; ++mt) {
#pragma unroll
        for (int reg = 0; reg < 4; ++reg) {
            const int rg = r0 + (w << 5) + (mt << 4) + (quad << 2) + reg;
            const int t = rg >> 4, b = rg & 15;
#pragma unroll
            for (int n = 0; n < 4; ++n) {
                const int col = c0 + (n << 4) + c;
                const int h = col >> 6, hd = col & 63;
                const float v = (acc[mt][n][reg] + bias[col]) * scale;
                Y[((size_t)(b * H + h) * ld + t) * HD + hd] = f2bf1(v);
            }
        }
    }
}

// ---------------------------------------------------------------------------
// bias columns + pad-tail zeroing, fully parallel (one store per thread).
// ---------------------------------------------------------------------------
#define FB_BIAS  8192
#define FB_KPAD  64512                       // 128 bh * 504 int4 (63 rows * 64 hd)
#define FB_VPAD  516096                      // 128 bh * 64 hd * 63 s
__global__ __launch_bounds__(256) void fill_bias(const float* __restrict__ bk,
    const float* __restrict__ bv,
    unsigned short* __restrict__ kbuf, unsigned short* __restrict__ vtbuf)
{
    const int idx = blockIdx.x * 256 + threadIdx.x;
    if (idx < FB_BIAS) {
        const int bh = idx >> 6, hd = idx & 63, h = bh & 7;
        kbuf[((size_t)bh * S1P + SRC) * HD + hd] = f2bf(bk[h * HD + hd]);
        vtbuf[((size_t)bh * HD + hd) * S1P + SRC] = f2bf(bv[h * HD + hd]);
    } else if (idx < FB_BIAS + FB_KPAD) {
        const int i = idx - FB_BIAS;
        const int bh = i / 504, o = i % 504;
        const int4 z = {0, 0, 0, 0};
        ((int4*)&kbuf[((size_t)bh * S1P + S1) * HD])[o] = z;
    } else if (idx < FB_BIAS + FB_KPAD + FB_VPAD) {
        const int i = idx - FB_BIAS - FB_KPAD;
        const int bh = i / 4032, r = i % 4032;
        const int hd = r / 63, s = S1 + r % 63;
        vtbuf[((size_t)bh * HD + hd) * S1P + s] = 0;
    }
}

// vbuf [bh][s][hd] -> vtbuf [bh][hd][s]
__global__ __launch_bounds__(256) void transpose_v(const unsigned short* __restrict__ vbuf,
    unsigned short* __restrict__ vtbuf)
{
    __shared__ __align__(16) unsigned short T[64][72];
    const int tid = threadIdx.x;
    const int s0  = blockIdx.x << 6;
    const int bh  = blockIdx.y;
#pragma unroll
    for (int i = 0; i < 2; ++i) {
        const int idx = tid + (i << 8);
        const int s = idx >> 3, q = (idx & 7) << 3;
        *(int4*)&T[s][q] = *(const int4*)&vbuf[((size_t)bh * SRC + s0 + s) * HD + q];
    }
    __syncthreads();
#pragma unroll
    for (int i = 0; i < 2; ++i) {
        const int idx = tid + (i << 8);
        const int hd = idx >> 3, sq = (idx & 7) << 3;
        unsigned short tmp[8];
#pragma unroll
        for (int j = 0; j < 8; ++j) tmp[j] = T[sq + j][hd];
        *(int4*)&vtbuf[((size_t)bh * HD + hd) * S1P + s0 + sq] = *(int4*)tmp;
    }
}

// ---------------------------------------------------------------------------
// Fused single-pass attention — restored R3 configuration (best measured):
// 512 threads / 8 waves / 2 blocks per CU, NO xcd swizzle (measured +15 us),
// rolled prefetch depth 1 WITH asm register pin so the compiler cannot sink
// the next-chunk loads past the current chunk's compute (VGPR=32/52 in prior
// rounds proved sinking).
//  - phase 1: 33 chunks over 8 waves
//  - phase 2: cross-wave row-sum reduction -> linv
//  - phase 3a: PV split (4 hd-slices x 2 K-halves), V prefetch depth 4
//  - phase 3b: paired b32 P reads (clean 537 MB WRITE in R5)
// ---------------------------------------------------------------------------
__global__ __launch_bounds__(512, 4) void attn_fused(
    const unsigned short* __restrict__ qbh,
    const unsigned short* __restrict__ kbuf,
    const unsigned short* __restrict__ vtbuf,
    const int* __restrict__ kpm,
    float* __restrict__ attn, unsigned short* __restrict__ ctx)
{
    __shared__ __align__(16) unsigned short P[16][PW];   // 67.84 KB
    __shared__ float cpart[16][68];                      // 4.25 KB
    __shared__ float sums[8][16];
    __shared__ float linv[16];
    const int tid = threadIdx.x;
    const int t0  = blockIdx.x << 4;
    const int bh  = blockIdx.y;
    const int bb  = bh >> 3;
    const int w = tid >> 6, lane = tid & 63, c = lane & 15, quad = lane >> 4;

    // Q A-fragments for this block's 16 rows (same for every wave)
    const unsigned short* qr = &qbh[((size_t)bh * TGT + t0 + c) * HD + (quad << 3)];
    short8 qa0 = *(const short8*)qr;
    short8 qa1 = *(const short8*)(qr + 32);

#define LOADK(D0, D1, M, CH) do {                                               \
        const unsigned short* kb_ = &kbuf[((size_t)bh * S1P + ((CH) << 6)) * HD]; \
        _Pragma("unroll")                                                       \
        for (int n_ = 0; n_ < 4; ++n_) {                                        \
            const unsigned short* kr_ = kb_ + ((n_ << 4) + c) * HD + (quad << 3); \
            D0[n_] = *(const short8*)kr_;                                       \
            D1[n_] = *(const short8*)(kr_ + 32);                                \
        }                                                                       \
        _Pragma("unroll")                                                       \
        for (int n_ = 0; n_ < 4; ++n_) {                                        \
            const int s_ = ((CH) << 6) + (n_ << 4) + c;                         \
            M[n_] = (s_ < SRC) ? (kpm[bb * SRC + s_] ? 3e38f : 0.f)             \
                               : ((s_ == SRC) ? 0.f : 3e38f);                   \
        }                                                                       \
    } while (0)

// force the prefetched fragments to be materialized HERE (anti-sink)
#define PIN(D0, D1) asm volatile("" :                                          \
        "+v"(D0[0]), "+v"(D0[1]), "+v"(D0[2]), "+v"(D0[3]),                     \
        "+v"(D1[0]), "+v"(D1[1]), "+v"(D1[2]), "+v"(D1[3]))

#define QK_COMPUTE(CH, B0, B1, M) do {                                          \
        const int s0_ = (CH) << 6;                                              \
        floatx4 sc_[4] = {};                                                    \
        _Pragma("unroll")                                                       \
        for (int n_ = 0; n_ < 4; ++n_) {                                        \
            sc_[n_] = __builtin_amdgcn_mfma_f32_16x16x32_bf16(qa0, B0[n_], sc_[n_], 0, 0, 0); \
            sc_[n_] = __builtin_amdgcn_mfma_f32_16x16x32_bf16(qa1, B1[n_], sc_[n_], 0, 0, 0); \
        }                                                                       \
        _Pragma("unroll")                                                       \
        for (int n_ = 0; n_ < 4; ++n_) {                                        \
            _Pragma("unroll")                                                   \
            for (int rg_ = 0; rg_ < 4; ++rg_) {                                 \
                const float p_ = __expf(sc_[n_][rg_] - M[n_]);                  \
                rs[rg_] += p_;                                                  \
                P[(quad << 2) + rg_][s0_ + (n_ << 4) + c] = f2bf1(p_);          \
            }                                                                   \
        }                                                                       \
    } while (0)

    // ---- phase 1: QK^T + exp, 33 chunks over 8 waves, prefetch depth 1 ----
    float rs[4] = {0.f, 0.f, 0.f, 0.f};
    short8 kb0[4], kb1[4];
    float mk[4];
    LOADK(kb0, kb1, mk, w);
    int ch;
    for (ch = w; ch + 8 < NCH; ch += 8) {
        short8 nb0[4], nb1[4];
        float nm[4];
        LOADK(nb0, nb1, nm, ch + 8);
        PIN(nb0, nb1);                        // loads issued before compute
        QK_COMPUTE(ch, kb0, kb1, mk);
#pragma unroll
        for (int n = 0; n < 4; ++n) { kb0[n] = nb0[n]; kb1[n] = nb1[n]; mk[n] = nm[n]; }
    }
    QK_COMPUTE(ch, kb0, kb1, mk);

    // ---- phase 2: row-sum reduction (over c lanes, then over 8 waves) ----
#pragma unroll
    for (int reg = 0; reg < 4; ++reg) {
        float v = rs[reg];
        v += __shfl_xor(v, 1); v += __shfl_xor(v, 2);
        v += __shfl_xor(v, 4); v += __shfl_xor(v, 8);
        rs[reg] = v;
    }
    if (c == 0) {
#pragma unroll
        for (int reg = 0; reg < 4; ++reg)
            sums[w][(quad << 2) + reg] = rs[reg];
    }
    __syncthreads();
    if (tid < 16) {
        float s = 0.f;
#pragma unroll
        for (int i = 0; i < 8; ++i) s += sums[i][tid];
        linv[tid] = 1.0f / s;
    }
    __syncthreads();

    // ---- phase 3a: PV. wave -> (hd-slice hs, K-half kh2); 33 units of 32
    // columns per half; V prefetch depth 4, tail unit loaded first. ----
    const int hs = w & 3, kh2 = w >> 2;
    const int base = kh2 * 1056;
    const unsigned short* vrow = &vtbuf[((size_t)bh * HD + (hs << 4) + c) * S1P + base];
#define LV(U) (*(const short8*)&vrow[((U) << 5) + (quad << 3)])
#define LP(U) (*(const short8*)&P[c][base + ((U) << 5) + (quad << 3)])
    floatx4 ca0 = {}, ca1 = {};
    short8 vt = LV(32);
    short8 v0 = LV(0), v1 = LV(1), v2 = LV(2), v3 = LV(3);
#pragma unroll
    for (int u = 0; u < 32; u += 4) {
        ca0 = __builtin_amdgcn_mfma_f32_16x16x32_bf16(LP(u),     v0, ca0, 0, 0, 0);
        ca1 = __builtin_amdgcn_mfma_f32_16x16x32_bf16(LP(u + 1), v1, ca1, 0, 0, 0);
        if (u < 28) { v0 = LV(u + 4); v1 = LV(u + 5); }
        ca0 = __builtin_amdgcn_mfma_f32_16x16x32_bf16(LP(u + 2), v2, ca0, 0, 0, 0);
        ca1 = __builtin_amdgcn_mfma_f32_16x16x32_bf16(LP(u + 3), v3, ca1, 0, 0, 0);
        if (u < 28) { v2 = LV(u + 6); v3 = LV(u + 7); }
    }
    ca0 = __builtin_amdgcn_mfma_f32_16x16x32_bf16(LP(32), vt, ca0, 0, 0, 0);
    if (kh2 == 1) {
#pragma unroll
        for (int reg = 0; reg < 4; ++reg)
            cpart[(quad << 2) + reg][(hs << 4) + c] = ca0[reg] + ca1[reg];
    }
    __syncthreads();
    if (kh2 == 0) {
#pragma unroll
        for (int reg = 0; reg < 4; ++reg) {
            const int row = (quad << 2) + reg;
            const float v = (ca0[reg] + ca1[reg] + cpart[row][(hs << 4) + c]) * linv[row];
            ctx[((size_t)bh * TGT + t0 + row) * HD + (hs << 4) + c] = f2bf1(v);
        }
    }

    // ---- phase 3b: normalized fp32 attn stores. 16 pairs of 64-col chunks
    // over 8 waves; each lane reads 2 P values per b32 LDS read. ----
    for (int p = w; p < 16; p += 8) {
        const int s0 = p << 7;
#pragma unroll
        for (int r = 0; r < 16; ++r) {
            const unsigned pk = *(const unsigned*)&P[r][s0 + (lane << 1)];
            const float li = linv[r];
            const size_t a = ((size_t)bh * TGT + t0 + r) * S1 + s0 + (lane << 1);
            attn[a]     = __uint_as_float((pk & 0xFFFFu) << 16) * li;
            attn[a + 1] = __uint_as_float(pk & 0xFFFF0000u) * li;
        }
    }
    if (w == 7 && lane < 16) {   // last real column s == 2048
        const float p = __uint_as_float((unsigned)P[lane][2048] << 16) * linv[lane];
        attn[((size_t)bh * TGT + t0 + lane) * S1 + 2048] = p;
    }
#undef LOADK
#undef PIN
#undef QK_COMPUTE
#undef LV
#undef LP
}

// ---------------------------------------------------------------------------
// out-projection: out[r][e] = ctx_row(r) . W[e][:] + bias[e]  (fp32 out)
// ---------------------------------------------------------------------------
__global__ __launch_bounds__(256) void outproj_gemm(const unsigned short* __restrict__ ctx,
    const unsigned short* __restrict__ W, const float* __restrict__ bias,
    float* __restrict__ out)
{
    __shared__ __align__(16) unsigned short As[128][72];
    __shared__ __align__(16) unsigned short Bs[64][72];
    const int tid = threadIdx.x;
    const int c0  = blockIdx.x << 6;
    const int r0  = blockIdx.y << 7;
    const int w   = tid >> 6, lane = tid & 63, c = lane & 15, quad = lane >> 4;
    floatx4 acc[2][4] = {};
    for (int k0 = 0; k0 < E; k0 += 64) {
        const int h = k0 >> 6;
#pragma unroll
        for (int i = 0; i < 4; ++i) {
            const int idx = tid + (i << 8);
            const int r = idx >> 3, q = (idx & 7) << 3;
            const int rg = r0 + r, t = rg >> 4, b = rg & 15;
            *(int4*)&As[r][q] = *(const int4*)&ctx[((size_t)(b * H + h) * TGT + t) * HD + q];
        }
#pragma unroll
        for (int i = 0; i < 2; ++i) {
            const int idx = tid + (i << 8);
            const int r = idx >> 3, q = (idx & 7) << 3;
            *(int4*)&Bs[r][q] = *(const int4*)&W[(size_t)(c0 + r) * E + k0 + q];
        }
        __syncthreads();
#pragma unroll
        for (int kh = 0; kh < 2; ++kh) {
            short8 a0 = *(const short8*)&As[(w << 5) + c][(kh << 5) + (quad << 3)];
            short8 a1 = *(const short8*)&As[(w << 5) + 16 + c][(kh << 5) + (quad << 3)];
#pragma unroll
            for (int n = 0; n < 4; ++n) {
                short8 b = *(const short8*)&Bs[(n << 4) + c][(kh << 5) + (quad << 3)];
                acc[0][n] = __builtin_amdgcn_mfma_f32_16x16x32_bf16(a0, b, acc[0][n], 0, 0, 0);
                acc[1][n] = __builtin_amdgcn_mfma_f32_16x16x32_bf16(a1, b, acc[1][n], 0, 0, 0);
            }
        }
        __syncthreads();
    }
#pragma unroll
    for (int mt = 0; mt < 2; ++mt) {
#pragma unroll
        for (int reg = 0; reg < 4; ++reg) {
            const int rg = r0 + (w << 5) + (mt << 4) + (quad << 2) + reg;
#pragma unroll
            for (int n = 0; n < 4; ++n) {
                const int col = c0 + (n << 4) + c;
                out[(size_t)rg * E + col] = acc[mt][n][reg] + bias[col];
            }
        }
    }
}

extern "C" void kernel_launch(void* const* d_in, const int* in_sizes, int n_in,
                              void* d_out, int out_size, void* d_ws, size_t ws_size,
                              hipStream_t stream)
{
    const float* query  = (const float*)d_in[0];
    const float* key    = (const float*)d_in[1];
    const float* value  = (const float*)d_in[2];
    const float* ipw    = (const float*)d_in[3];
    const float* ipb    = (const float*)d_in[4];
    const float* bias_k = (const float*)d_in[5];
    const float* bias_v = (const float*)d_in[6];
    const float* opw    = (const float*)d_in[7];
    const float* opb    = (const float*)d_in[8];
    const int*   kpm    = (const int*)d_in[9];

    float* out  = (float*)d_out;
    float* attn = out + (size_t)TGT * NB * E;                 // 128*512*2049 fp32

    // scratch bf16 buffers that die before the fused attention live in attn
    unsigned short* k_bf = (unsigned short*)attn;             // key converted  [32768][512]
    unsigned short* v_bf = k_bf + (size_t)16777216;           // value converted
    unsigned short* vbuf = v_bf + (size_t)16777216;           // V proj [bh][s][hd]

    char* ws = (char*)d_ws;
    unsigned short* q_bf  = (unsigned short*)ws;                       // [8192][512]
    unsigned short* wi_bf = q_bf  + (size_t)4194304;                   // [3E][E]
    unsigned short* wo_bf = wi_bf + (size_t)786432;                    // [E][E]
    unsigned short* qbh   = wo_bf + (size_t)262144;                    // [bh][t][hd]
    unsigned short* kbuf  = qbh   + (size_t)4194304;                   // [bh][S1P][hd]
    unsigned short* vtbuf = kbuf  + (size_t)17301504;                  // [bh][hd][S1P]
    unsigned short* ctx   = vtbuf + (size_t)17301504;                  // [bh][t][hd]

    cvt_bf16<<<dim3(2048), 256, 0, stream>>>(query, q_bf, 524288);
    cvt_bf16<<<dim3(8192), 256, 0, stream>>>(key,   k_bf, 2097152);
    cvt_bf16<<<dim3(8192), 256, 0, stream>>>(value, v_bf, 2097152);
    cvt_bf16<<<dim3(384),  256, 0, stream>>>(ipw,   wi_bf, 98304);
    cvt_bf16<<<dim3(128),  256, 0, stream>>>(opw,   wo_bf, 32768);

    proj_gemm<<<dim3(8, 64),  256, 0, stream>>>(q_bf, wi_bf,          ipb,         qbh,  TGT, 0.125f);
    proj_gemm<<<dim3(8, 256), 256, 0, stream>>>(k_bf, wi_bf + 262144, ipb + E,     kbuf, S1P, 1.0f);
    proj_gemm<<<dim3(8, 256), 256, 0, stream>>>(v_bf, wi_bf + 524288, ipb + 2 * E, vbuf, SRC, 1.0f);

    fill_bias<<<dim3(2300), 256, 0, stream>>>(bias_k, bias_v, kbuf, vtbuf);
    transpose_v<<<dim3(32, 128), 256, 0, stream>>>(vbuf, vtbuf);

    attn_fused<<<dim3(32, 128), 512, 0, stream>>>(qbh, kbuf, vtbuf, kpm, attn, ctx);
    outproj_gemm<<<dim3(8, 64), 256, 0, stream>>>(ctx, wo_bf, opb, out);
}

// Round 8
// 1024.925 us; speedup vs baseline: 1.1330x; 1.0490x over previous
//
#include <hip/hip_runtime.h>
#include <hip/hip_bf16.h>

#define E    512
#define H    8
#define HD   64
#define TGT  512
#define SRC  2048
#define S1   2049
#define S1P  2112     // padded source length (33 chunks of 64)
#define NB   16
#define BH   128
#define NCH  33
#define PW   2120     // P row stride in shorts: 4240 B = 16B-aligned, bank-uniform

typedef __attribute__((ext_vector_type(8))) short short8;
typedef __attribute__((ext_vector_type(4))) float floatx4;

__device__ __forceinline__ unsigned short f2bf(float x) {
    unsigned u = __float_as_uint(x);
    u = (u + 0x7FFF + ((u >> 16) & 1)) >> 16;   // round-to-nearest-even
    return (unsigned short)u;
}

// single fp32 -> bf16 RNE via hardware cvt
__device__ __forceinline__ unsigned short f2bf1(float x) {
    __hip_bfloat16 h = __float2bfloat16(x);
    return *(unsigned short*)&h;
}

// pack 8 fp32 -> 8 bf16 (RNE) via compiler-fused v_cvt_pk_bf16_f32
__device__ __forceinline__ int4 cvt8(const float4 f0, const float4 f1) {
    __hip_bfloat162 o[4];
    o[0] = __float22bfloat162_rn({f0.x, f0.y});
    o[1] = __float22bfloat162_rn({f0.z, f0.w});
    o[2] = __float22bfloat162_rn({f1.x, f1.y});
    o[3] = __float22bfloat162_rn({f1.z, f1.w});
    return *(int4*)o;
}

// ---------------------------------------------------------------------------
// fp32 -> bf16 conversion, 8 elements/thread (packed cvt_pk)
// ---------------------------------------------------------------------------
__global__ __launch_bounds__(256) void cvt_bf16(const float* __restrict__ src,
    unsigned short* __restrict__ dst, const int n8)
{
    const int i = blockIdx.x * 256 + threadIdx.x;
    if (i >= n8) return;
    const float4 f0 = ((const float4*)src)[(size_t)i * 2];
    const float4 f1 = ((const float4*)src)[(size_t)i * 2 + 1];
    ((int4*)dst)[i] = cvt8(f0, f1);
}

// ---------------------------------------------------------------------------
// merged in-projection for q/k/v (blockIdx.z selects input/output).
//   z=0: q -> qbh [bh][t][hd], scaled 0.125 (only 64 y-blocks)
//   z=1: k -> kbuf [bh][s][hd] (ld = S1P)
//   z=2: v -> vtbuf [bh][hd][s] TRANSPOSED via LDS re-stage in the epilogue
//        (replaces the standalone transpose_v kernel + vbuf roundtrip)
// ---------------------------------------------------------------------------
__global__ __launch_bounds__(256) void proj_all(
    const unsigned short* __restrict__ q_bf, const unsigned short* __restrict__ k_bf,
    const unsigned short* __restrict__ v_bf, const unsigned short* __restrict__ wi,
    const float* __restrict__ ipb,
    unsigned short* __restrict__ qbh, unsigned short* __restrict__ kbuf,
    unsigned short* __restrict__ vtbuf)
{
    const int z = blockIdx.z;
    if (z == 0 && blockIdx.y >= 64) return;
    __shared__ __align__(16) unsigned short As[128][72];
    __shared__ __align__(16) unsigned short Bs[64][72];
    const unsigned short* X = (z == 0) ? q_bf : (z == 1) ? k_bf : v_bf;
    const unsigned short* W = wi + (size_t)z * 262144;
    const float* bias = ipb + z * E;
    const int tid  = threadIdx.x;
    const int c0   = blockIdx.x << 6;
    const int r0   = blockIdx.y << 7;
    const int w    = tid >> 6, lane = tid & 63, c = lane & 15, quad = lane >> 4;
    floatx4 acc[2][4] = {};
    for (int k0 = 0; k0 < E; k0 += 64) {
#pragma unroll
        for (int i = 0; i < 4; ++i) {
            const int idx = tid + (i << 8);
            const int r = idx >> 3, q = (idx & 7) << 3;
            *(int4*)&As[r][q] = *(const int4*)&X[(size_t)(r0 + r) * E + k0 + q];
        }
#pragma unroll
        for (int i = 0; i < 2; ++i) {
            const int idx = tid + (i << 8);
            const int r = idx >> 3, q = (idx & 7) << 3;
            *(int4*)&Bs[r][q] = *(const int4*)&W[(size_t)(c0 + r) * E + k0 + q];
        }
        __syncthreads();
#pragma unroll
        for (int kh = 0; kh < 2; ++kh) {
            short8 a0 = *(const short8*)&As[(w << 5) + c][(kh << 5) + (quad << 3)];
            short8 a1 = *(const short8*)&As[(w << 5) + 16 + c][(kh << 5) + (quad << 3)];
#pragma unroll
            for (int n = 0; n < 4; ++n) {
                short8 b = *(const short8*)&Bs[(n << 4) + c][(kh << 5) + (quad << 3)];
                acc[0][n] = __builtin_amdgcn_mfma_f32_16x16x32_bf16(a0, b, acc[0][n], 0, 0, 0);
                acc[1][n] = __builtin_amdgcn_mfma_f32_16x16x32_bf16(a1, b, acc[1][n], 0, 0, 0);
            }
        }
        __syncthreads();
    }
    if (z == 2) {
        // ---- transposed epilogue: acc tile -> As (bf16), then each thread
        // gathers 8 consecutive s for one (b,hd) -> single int4 store ----
        const int h = c0 >> 6;
#pragma unroll
        for (int mt = 0; mt < 2; ++mt) {
#pragma unroll
            for (int reg = 0; reg < 4; ++reg) {
                const int local = (w << 5) + (mt << 4) + (quad << 2) + reg;
#pragma unroll
                for (int n = 0; n < 4; ++n) {
                    const int hd = (n << 4) + c;
                    As[local][hd] = f2bf1(acc[mt][n][reg] + bias[c0 + hd]);
                }
            }
        }
        __syncthreads();
        const int s0v = blockIdx.y << 3;       // rows rg: s = s0v + j, b = rg&15
#pragma unroll
        for (int i = 0; i < 4; ++i) {
            const int idx = tid + (i << 8);    // 0..1023
            const int b = idx & 15, hd = idx >> 4;
            unsigned short tmp[8];
#pragma unroll
            for (int j = 0; j < 8; ++j) tmp[j] = As[(j << 4) + b][hd];
            *(int4*)&vtbuf[((size_t)(b * H + h) * HD + hd) * S1P + s0v] = *(int4*)tmp;
        }
        return;
    }
    unsigned short* Y = (z == 0) ? qbh : kbuf;
    const int ld = (z == 0) ? TGT : S1P;
    const float scale = (z == 0) ? 0.125f : 1.0f;
#pragma unroll
    for (int mt = 0; mt < 2; ++mt) {
#pragma unroll
        for (int reg = 0; reg < 4; ++reg) {
            const int rg = r0 + (w << 5) + (mt << 4) + (quad << 2) + reg;
            const int t = rg >> 4, b = rg & 15;
#pragma unroll
            for (int n = 0; n < 4; ++n) {
                const int col = c0 + (n << 4) + c;
                const int h = col >> 6, hd = col & 63;
                const float v = (acc[mt][n][reg] + bias[col]) * scale;
                Y[((size_t)(b * H + h) * ld + t) * HD + hd] = f2bf1(v);
            }
        }
    }
}

// ---------------------------------------------------------------------------
// bias columns + pad-tail zeroing, fully parallel (one store per thread).
// ---------------------------------------------------------------------------
#define FB_BIAS  8192
#define FB_KPAD  64512                       // 128 bh * 504 int4 (63 rows * 64 hd)
#define FB_VPAD  516096                      // 128 bh * 64 hd * 63 s
__global__ __launch_bounds__(256) void fill_bias(const float* __restrict__ bk,
    const float* __restrict__ bv,
    unsigned short* __restrict__ kbuf, unsigned short* __restrict__ vtbuf)
{
    const int idx = blockIdx.x * 256 + threadIdx.x;
    if (idx < FB_BIAS) {
        const int bh = idx >> 6, hd = idx & 63, h = bh & 7;
        kbuf[((size_t)bh * S1P + SRC) * HD + hd] = f2bf(bk[h * HD + hd]);
        vtbuf[((size_t)bh * HD + hd) * S1P + SRC] = f2bf(bv[h * HD + hd]);
    } else if (idx < FB_BIAS + FB_KPAD) {
        const int i = idx - FB_BIAS;
        const int bh = i / 504, o = i % 504;
        const int4 z = {0, 0, 0, 0};
        ((int4*)&kbuf[((size_t)bh * S1P + S1) * HD])[o] = z;
    } else if (idx < FB_BIAS + FB_KPAD + FB_VPAD) {
        const int i = idx - FB_BIAS - FB_KPAD;
        const int bh = i / 4032, r = i % 4032;
        const int hd = r / 63, s = S1 + r % 63;
        vtbuf[((size_t)bh * HD + hd) * S1P + s] = 0;
    }
}

// ---------------------------------------------------------------------------
// Fused single-pass attention — R7 configuration (best measured):
// 512 threads / 8 waves / 2 blocks per CU, no xcd swizzle,
// rolled prefetch depth 1 with asm register pin (anti-sink).
// ---------------------------------------------------------------------------
__global__ __launch_bounds__(512, 4) void attn_fused(
    const unsigned short* __restrict__ qbh,
    const unsigned short* __restrict__ kbuf,
    const unsigned short* __restrict__ vtbuf,
    const int* __restrict__ kpm,
    float* __restrict__ attn, unsigned short* __restrict__ ctx)
{
    __shared__ __align__(16) unsigned short P[16][PW];   // 67.84 KB
    __shared__ float cpart[16][68];                      // 4.25 KB
    __shared__ float sums[8][16];
    __shared__ float linv[16];
    const int tid = threadIdx.x;
    const int t0  = blockIdx.x << 4;
    const int bh  = blockIdx.y;
    const int bb  = bh >> 3;
    const int w = tid >> 6, lane = tid & 63, c = lane & 15, quad = lane >> 4;

    // Q A-fragments for this block's 16 rows (same for every wave)
    const unsigned short* qr = &qbh[((size_t)bh * TGT + t0 + c) * HD + (quad << 3)];
    short8 qa0 = *(const short8*)qr;
    short8 qa1 = *(const short8*)(qr + 32);

#define LOADK(D0, D1, M, CH) do {                                               \
        const unsigned short* kb_ = &kbuf[((size_t)bh * S1P + ((CH) << 6)) * HD]; \
        _Pragma("unroll")                                                       \
        for (int n_ = 0; n_ < 4; ++n_) {                                        \
            const unsigned short* kr_ = kb_ + ((n_ << 4) + c) * HD + (quad << 3); \
            D0[n_] = *(const short8*)kr_;                                       \
            D1[n_] = *(const short8*)(kr_ + 32);                                \
        }                                                                       \
        _Pragma("unroll")                                                       \
        for (int n_ = 0; n_ < 4; ++n_) {                                        \
            const int s_ = ((CH) << 6) + (n_ << 4) + c;                         \
            M[n_] = (s_ < SRC) ? (kpm[bb * SRC + s_] ? 3e38f : 0.f)             \
                               : ((s_ == SRC) ? 0.f : 3e38f);                   \
        }                                                                       \
    } while (0)

// force the prefetched fragments to be materialized HERE (anti-sink)
#define PIN(D0, D1) asm volatile("" :                                          \
        "+v"(D0[0]), "+v"(D0[1]), "+v"(D0[2]), "+v"(D0[3]),                     \
        "+v"(D1[0]), "+v"(D1[1]), "+v"(D1[2]), "+v"(D1[3]))

#define QK_COMPUTE(CH, B0, B1, M) do {                                          \
        const int s0_ = (CH) << 6;                                              \
        floatx4 sc_[4] = {};                                                    \
        _Pragma("unroll")                                                       \
        for (int n_ = 0; n_ < 4; ++n_) {                                        \
            sc_[n_] = __builtin_amdgcn_mfma_f32_16x16x32_bf16(qa0, B0[n_], sc_[n_], 0, 0, 0); \
            sc_[n_] = __builtin_amdgcn_mfma_f32_16x16x32_bf16(qa1, B1[n_], sc_[n_], 0, 0, 0); \
        }                                                                       \
        _Pragma("unroll")                                                       \
        for (int n_ = 0; n_ < 4; ++n_) {                                        \
            _Pragma("unroll")                                                   \
            for (int rg_ = 0; rg_ < 4; ++rg_) {                                 \
                const float p_ = __expf(sc_[n_][rg_] - M[n_]);                  \
                rs[rg_] += p_;                                                  \
                P[(quad << 2) + rg_][s0_ + (n_ << 4) + c] = f2bf1(p_);          \
            }                                                                   \
        }                                                                       \
    } while (0)

    // ---- phase 1: QK^T + exp, 33 chunks over 8 waves, prefetch depth 1 ----
    float rs[4] = {0.f, 0.f, 0.f, 0.f};
    short8 kb0[4], kb1[4];
    float mk[4];
    LOADK(kb0, kb1, mk, w);
    int ch;
    for (ch = w; ch + 8 < NCH; ch += 8) {
        short8 nb0[4], nb1[4];
        float nm[4];
        LOADK(nb0, nb1, nm, ch + 8);
        PIN(nb0, nb1);                        // loads issued before compute
        QK_COMPUTE(ch, kb0, kb1, mk);
#pragma unroll
        for (int n = 0; n < 4; ++n) { kb0[n] = nb0[n]; kb1[n] = nb1[n]; mk[n] = nm[n]; }
    }
    QK_COMPUTE(ch, kb0, kb1, mk);

    // ---- phase 2: row-sum reduction (over c lanes, then over 8 waves) ----
#pragma unroll
    for (int reg = 0; reg < 4; ++reg) {
        float v = rs[reg];
        v += __shfl_xor(v, 1); v += __shfl_xor(v, 2);
        v += __shfl_xor(v, 4); v += __shfl_xor(v, 8);
        rs[reg] = v;
    }
    if (c == 0) {
#pragma unroll
        for (int reg = 0; reg < 4; ++reg)
            sums[w][(quad << 2) + reg] = rs[reg];
    }
    __syncthreads();
    if (tid < 16) {
        float s = 0.f;
#pragma unroll
        for (int i = 0; i < 8; ++i) s += sums[i][tid];
        linv[tid] = 1.0f / s;
    }
    __syncthreads();

    // ---- phase 3a: PV. wave -> (hd-slice hs, K-half kh2); 33 units of 32
    // columns per half; V prefetch depth 4, tail unit loaded first. ----
    const int hs = w & 3, kh2 = w >> 2;
    const int base = kh2 * 1056;
    const unsigned short* vrow = &vtbuf[((size_t)bh * HD + (hs << 4) + c) * S1P + base];
#define LV(U) (*(const short8*)&vrow[((U) << 5) + (quad << 3)])
#define LP(U) (*(const short8*)&P[c][base + ((U) << 5) + (quad << 3)])
    floatx4 ca0 = {}, ca1 = {};
    short8 vt = LV(32);
    short8 v0 = LV(0), v1 = LV(1), v2 = LV(2), v3 = LV(3);
#pragma unroll
    for (int u = 0; u < 32; u += 4) {
        ca0 = __builtin_amdgcn_mfma_f32_16x16x32_bf16(LP(u),     v0, ca0, 0, 0, 0);
        ca1 = __builtin_amdgcn_mfma_f32_16x16x32_bf16(LP(u + 1), v1, ca1, 0, 0, 0);
        if (u < 28) { v0 = LV(u + 4); v1 = LV(u + 5); }
        ca0 = __builtin_amdgcn_mfma_f32_16x16x32_bf16(LP(u + 2), v2, ca0, 0, 0, 0);
        ca1 = __builtin_amdgcn_mfma_f32_16x16x32_bf16(LP(u + 3), v3, ca1, 0, 0, 0);
        if (u < 28) { v2 = LV(u + 6); v3 = LV(u + 7); }
    }
    ca0 = __builtin_amdgcn_mfma_f32_16x16x32_bf16(LP(32), vt, ca0, 0, 0, 0);
    if (kh2 == 1) {
#pragma unroll
        for (int reg = 0; reg < 4; ++reg)
            cpart[(quad << 2) + reg][(hs << 4) + c] = ca0[reg] + ca1[reg];
    }
    __syncthreads();
    if (kh2 == 0) {
#pragma unroll
        for (int reg = 0; reg < 4; ++reg) {
            const int row = (quad << 2) + reg;
            const float v = (ca0[reg] + ca1[reg] + cpart[row][(hs << 4) + c]) * linv[row];
            ctx[((size_t)bh * TGT + t0 + row) * HD + (hs << 4) + c] = f2bf1(v);
        }
    }

    // ---- phase 3b: normalized fp32 attn stores. 16 pairs of 64-col chunks
    // over 8 waves; each lane reads 2 P values per b32 LDS read. ----
    for (int p = w; p < 16; p += 8) {
        const int s0 = p << 7;
#pragma unroll
        for (int r = 0; r < 16; ++r) {
            const unsigned pk = *(const unsigned*)&P[r][s0 + (lane << 1)];
            const float li = linv[r];
            const size_t a = ((size_t)bh * TGT + t0 + r) * S1 + s0 + (lane << 1);
            attn[a]     = __uint_as_float((pk & 0xFFFFu) << 16) * li;
            attn[a + 1] = __uint_as_float(pk & 0xFFFF0000u) * li;
        }
    }
    if (w == 7 && lane < 16) {   // last real column s == 2048
        const float p = __uint_as_float((unsigned)P[lane][2048] << 16) * linv[lane];
        attn[((size_t)bh * TGT + t0 + lane) * S1 + 2048] = p;
    }
#undef LOADK
#undef PIN
#undef QK_COMPUTE
#undef LV
#undef LP
}

// ---------------------------------------------------------------------------
// out-projection: out[r][e] = ctx_row(r) . W[e][:] + bias[e]  (fp32 out)
// ---------------------------------------------------------------------------
__global__ __launch_bounds__(256) void outproj_gemm(const unsigned short* __restrict__ ctx,
    const unsigned short* __restrict__ W, const float* __restrict__ bias,
    float* __restrict__ out)
{
    __shared__ __align__(16) unsigned short As[128][72];
    __shared__ __align__(16) unsigned short Bs[64][72];
    const int tid = threadIdx.x;
    const int c0  = blockIdx.x << 6;
    const int r0  = blockIdx.y << 7;
    const int w   = tid >> 6, lane = tid & 63, c = lane & 15, quad = lane >> 4;
    floatx4 acc[2][4] = {};
    for (int k0 = 0; k0 < E; k0 += 64) {
        const int h = k0 >> 6;
#pragma unroll
        for (int i = 0; i < 4; ++i) {
            const int idx = tid + (i << 8);
            const int r = idx >> 3, q = (idx & 7) << 3;
            const int rg = r0 + r, t = rg >> 4, b = rg & 15;
            *(int4*)&As[r][q] = *(const int4*)&ctx[((size_t)(b * H + h) * TGT + t) * HD + q];
        }
#pragma unroll
        for (int i = 0; i < 2; ++i) {
            const int idx = tid + (i << 8);
            const int r = idx >> 3, q = (idx & 7) << 3;
            *(int4*)&Bs[r][q] = *(const int4*)&W[(size_t)(c0 + r) * E + k0 + q];
        }
        __syncthreads();
#pragma unroll
        for (int kh = 0; kh < 2; ++kh) {
            short8 a0 = *(const short8*)&As[(w << 5) + c][(kh << 5) + (quad << 3)];
            short8 a1 = *(const short8*)&As[(w << 5) + 16 + c][(kh << 5) + (quad << 3)];
#pragma unroll
            for (int n = 0; n < 4; ++n) {
                short8 b = *(const short8*)&Bs[(n << 4) + c][(kh << 5) + (quad << 3)];
                acc[0][n] = __builtin_amdgcn_mfma_f32_16x16x32_bf16(a0, b, acc[0][n], 0, 0, 0);
                acc[1][n] = __builtin_amdgcn_mfma_f32_16x16x32_bf16(a1, b, acc[1][n], 0, 0, 0);
            }
        }
        __syncthreads();
    }
#pragma unroll
    for (int mt = 0; mt < 2; ++mt) {
#pragma unroll
        for (int reg = 0; reg < 4; ++reg) {
            const int rg = r0 + (w << 5) + (mt << 4) + (quad << 2) + reg;
#pragma unroll
            for (int n = 0; n < 4; ++n) {
                const int col = c0 + (n << 4) + c;
                out[(size_t)rg * E + col] = acc[mt][n][reg] + bias[col];
            }
        }
    }
}

extern "C" void kernel_launch(void* const* d_in, const int* in_sizes, int n_in,
                              void* d_out, int out_size, void* d_ws, size_t ws_size,
                              hipStream_t stream)
{
    const float* query  = (const float*)d_in[0];
    const float* key    = (const float*)d_in[1];
    const float* value  = (const float*)d_in[2];
    const float* ipw    = (const float*)d_in[3];
    const float* ipb    = (const float*)d_in[4];
    const float* bias_k = (const float*)d_in[5];
    const float* bias_v = (const float*)d_in[6];
    const float* opw    = (const float*)d_in[7];
    const float* opb    = (const float*)d_in[8];
    const int*   kpm    = (const int*)d_in[9];

    float* out  = (float*)d_out;
    float* attn = out + (size_t)TGT * NB * E;                 // 128*512*2049 fp32

    // scratch bf16 buffers that die before the fused attention live in attn
    unsigned short* k_bf = (unsigned short*)attn;             // key converted  [32768][512]
    unsigned short* v_bf = k_bf + (size_t)16777216;           // value converted

    char* ws = (char*)d_ws;
    unsigned short* q_bf  = (unsigned short*)ws;                       // [8192][512]
    unsigned short* wi_bf = q_bf  + (size_t)4194304;                   // [3E][E]
    unsigned short* wo_bf = wi_bf + (size_t)786432;                    // [E][E]
    unsigned short* qbh   = wo_bf + (size_t)262144;                    // [bh][t][hd]
    unsigned short* kbuf  = qbh   + (size_t)4194304;                   // [bh][S1P][hd]
    unsigned short* vtbuf = kbuf  + (size_t)17301504;                  // [bh][hd][S1P]
    unsigned short* ctx   = vtbuf + (size_t)17301504;                  // [bh][t][hd]

    cvt_bf16<<<dim3(2048), 256, 0, stream>>>(query, q_bf, 524288);
    cvt_bf16<<<dim3(8192), 256, 0, stream>>>(key,   k_bf, 2097152);
    cvt_bf16<<<dim3(8192), 256, 0, stream>>>(value, v_bf, 2097152);
    cvt_bf16<<<dim3(384),  256, 0, stream>>>(ipw,   wi_bf, 98304);
    cvt_bf16<<<dim3(128),  256, 0, stream>>>(opw,   wo_bf, 32768);

    proj_all<<<dim3(8, 256, 3), 256, 0, stream>>>(q_bf, k_bf, v_bf, wi_bf, ipb,
                                                  qbh, kbuf, vtbuf);

    fill_bias<<<dim3(2300), 256, 0, stream>>>(bias_k, bias_v, kbuf, vtbuf);

    attn_fused<<<dim3(32, 128), 512, 0, stream>>>(qbh, kbuf, vtbuf, kpm, attn, ctx);
    outproj_gemm<<<dim3(8, 64), 256, 0, stream>>>(ctx, wo_bf, opb, out);
}